// Round 1
// baseline (4124.306 us; speedup 1.0000x reference)
//
#include <hip/hip_runtime.h>
#include <hip/hip_bf16.h>
#include <math.h>

// ---------------- model constants ----------------
constexpr int BATCH = 32;
constexpr int NHEAD = 12;
constexpr int DEPTH = 12;
constexpr int L0TOK = 196;
constexpr int MAXK = 138;
constexpr float ATT_SCALE = 0.125f;

// workspace layout (float-slot offsets)
constexpr size_t SZ_T = (size_t)BATCH * 197 * 768;            // 4,841,472
constexpr size_t OFF_T0 = 0;
constexpr size_t OFF_T1 = SZ_T;
constexpr size_t OFF_C32 = 2 * SZ_T;                          // 14,524,416 floats
constexpr size_t OFF_ABF = OFF_C32 + (size_t)BATCH * 197 * 2304;   // bf16 activations (2,420,736 slots)
constexpr size_t OFF_WL  = OFF_ABF + 2420736;                 // bf16 weights: 7,667,712 bf16 = 3,833,856 float slots
constexpr size_t OFF_GLOB  = OFF_WL + 3833856;
constexpr size_t OFF_SCORE = OFF_GLOB + (size_t)BATCH * 384;
constexpr size_t OFF_KIDX  = OFF_SCORE + (size_t)BATCH * L0TOK;
constexpr size_t OFF_CLS   = OFF_KIDX + (size_t)BATCH * 140;

// per-layer bf16 weight sub-offsets (bf16-element units)
constexpr size_t W_QKV  = 0;               // 2304*768 = 1,769,472
constexpr size_t W_PROJ = 1769472;         // 768*768  =   589,824
constexpr size_t W_FC1  = 2359296;         // 3072*768 = 2,359,296
constexpr size_t W_FC2  = 4718592;         // 768*3072 = 2,359,296
constexpr size_t W_PIN  = 7077888;         // 768*768  =   589,824
// totals: 7,077,888 (non-prune) / 7,667,712 (prune) bf16 elems

typedef __attribute__((ext_vector_type(8))) short short8;
typedef __attribute__((ext_vector_type(4))) float float4v;

__device__ __forceinline__ float gelu_f(float x) {
    return 0.5f * x * (1.0f + erff(x * 0.7071067811865476f));
}
__device__ __forceinline__ float dot4(float4 a, float4 b) {
    return a.x * b.x + a.y * b.y + a.z * b.z + a.w * b.w;
}
__device__ __forceinline__ float bf2f(short s) {
    return __uint_as_float(((unsigned)(unsigned short)s) << 16);
}

// async 16B global->LDS (DMA, no VGPR round trip)
__device__ __forceinline__ void load_lds16(const void* g, void* l) {
    __builtin_amdgcn_global_load_lds(
        (const __attribute__((address_space(1))) unsigned int*)g,
        (__attribute__((address_space(3))) unsigned int*)l, 16, 0, 0);
}

// ---------------- fp32 -> bf16 weight conversion ----------------
__global__ void cvt_kernel(const float* __restrict__ src, __hip_bfloat16* __restrict__ dst, int n) {
    int i = (blockIdx.x * 256 + threadIdx.x) * 4;
    if (i >= n) return;
    float4 v = *(const float4*)(src + i);
    dst[i + 0] = __float2bfloat16(v.x);
    dst[i + 1] = __float2bfloat16(v.y);
    dst[i + 2] = __float2bfloat16(v.z);
    dst[i + 3] = __float2bfloat16(v.w);
}
static inline void cvt(hipStream_t st, const float* s, __hip_bfloat16* d, size_t n) {
    cvt_kernel<<<(n / 4 + 255) / 256, 256, 0, st>>>(s, d, (int)n);
}

// fused per-layer weight convert: qkv|proj|fc1|fc2[|pin] in one launch.
// All boundaries are multiples of 8 so an 8-elem span never straddles matrices.
__global__ void cvt_layer_kernel(const float* __restrict__ wqkv, const float* __restrict__ wproj,
                                 const float* __restrict__ wfc1, const float* __restrict__ wfc2,
                                 const float* __restrict__ wpin, __hip_bfloat16* __restrict__ dst) {
    size_t i = ((size_t)blockIdx.x * 256 + threadIdx.x) * 8;
    const float* src;
    size_t off;
    if (i < W_PROJ)      { src = wqkv;  off = i; }
    else if (i < W_FC1)  { src = wproj; off = i - W_PROJ; }
    else if (i < W_FC2)  { src = wfc1;  off = i - W_FC1; }
    else if (i < W_PIN)  { src = wfc2;  off = i - W_FC2; }
    else                 { src = wpin;  off = i - W_PIN; }
    float4 a = *(const float4*)(src + off);
    float4 b = *(const float4*)(src + off + 4);
    union { short8 v; __hip_bfloat16 h[8]; } u;
    u.h[0] = __float2bfloat16(a.x); u.h[1] = __float2bfloat16(a.y);
    u.h[2] = __float2bfloat16(a.z); u.h[3] = __float2bfloat16(a.w);
    u.h[4] = __float2bfloat16(b.x); u.h[5] = __float2bfloat16(b.y);
    u.h[6] = __float2bfloat16(b.z); u.h[7] = __float2bfloat16(b.w);
    *(short8*)(dst + i) = u.v;
}

// ---------------- patch rearrange (bf16 out) ----------------
__global__ void patch_kernel(const float* __restrict__ x, __hip_bfloat16* __restrict__ p) {
    int idx = blockIdx.x * 256 + threadIdx.x;
    int c = idx % 768;
    int rest = idx / 768;
    int l = rest % 196;
    int b = rest / 196;
    int ch = c >> 8;
    int py = (c & 255) >> 4;
    int px = c & 15;
    int gy = l / 14, gx = l % 14;
    p[idx] = __float2bfloat16(
        x[(((size_t)b * 3 + ch) * 224 + gy * 16 + py) * 224 + gx * 16 + px]);
}

// ---------------- assemble t = [cls; patches] + pos (fp32) ----------------
__global__ void assemble_kernel(const float* __restrict__ pe, const float* __restrict__ cls,
                                const float* __restrict__ pos, float* __restrict__ t) {
    int row = blockIdx.x;
    int b = row / 197, l = row % 197;
    for (int c = threadIdx.x; c < 768; c += 256) {
        float v = (l == 0) ? cls[c] : pe[((size_t)(b * 196 + l - 1)) * 768 + c];
        t[(size_t)row * 768 + c] = v + pos[l * 768 + c];
    }
}

// ---------------- layernorm, templated output type ----------------
template <typename OT>
__global__ __launch_bounds__(256)
void ln_kernel(const float* __restrict__ src, OT* __restrict__ dst,
               const float* __restrict__ g, const float* __restrict__ bb,
               int R, int SB, int SO, int DB, int DO_) {
    __shared__ float red[256];
    int row = blockIdx.x;
    int b = row / R, r = row % R;
    const float* sp = src + ((size_t)b * SB + SO + r) * 768;
    OT* dp = dst + ((size_t)b * DB + DO_ + r) * 768;
    int tid = threadIdx.x;
    float x0 = sp[tid], x1 = sp[tid + 256], x2 = sp[tid + 512];
    red[tid] = x0 + x1 + x2;
    __syncthreads();
    for (int st = 128; st > 0; st >>= 1) {
        if (tid < st) red[tid] += red[tid + st];
        __syncthreads();
    }
    float mean = red[0] * (1.0f / 768.0f);
    __syncthreads();
    float d0 = x0 - mean, d1 = x1 - mean, d2 = x2 - mean;
    red[tid] = d0 * d0 + d1 * d1 + d2 * d2;
    __syncthreads();
    for (int st = 128; st > 0; st >>= 1) {
        if (tid < st) red[tid] += red[tid + st];
        __syncthreads();
    }
    float inv = rsqrtf(red[0] * (1.0f / 768.0f) + 1e-6f);
    dp[tid]       = (OT)(d0 * inv * g[tid]       + bb[tid]);
    dp[tid + 256] = (OT)(d1 * inv * g[tid + 256] + bb[tid + 256]);
    dp[tid + 512] = (OT)(d2 * inv * g[tid + 512] + bb[tid + 512]);
}

// ---------------- MFMA GEMM: C = A(MxK,bf16) @ W(NxK,bf16)^T + bias ----------------
// 128x128 tile, 256 thr (4 waves, 2x2 of 64x64), K-step 32, m97 structure.
// EPI: 0=bias, 1=bias+gelu, 2=bias+residual.  N must be a multiple of 128; K of 32.
template <int EPI, typename CT>
__global__ __launch_bounds__(256)
void gemm_mfma(const __hip_bfloat16* __restrict__ A, const __hip_bfloat16* __restrict__ W,
               const float* __restrict__ bias, const float* __restrict__ res,
               CT* __restrict__ C, int M, int N, int K) {
    __shared__ __hip_bfloat16 As[128 * 32];
    __shared__ __hip_bfloat16 Bs[128 * 32];
    int tid = threadIdx.x;
    int lane = tid & 63;
    int wave = tid >> 6;
    int m0 = blockIdx.y * 128, n0 = blockIdx.x * 128;
    int wm = (wave >> 1) * 64, wn = (wave & 1) * 64;

    int c0 = tid, c1 = tid + 256;
    int ra0 = c0 >> 2, ka0 = (c0 & 3) << 3;
    int ra1 = c1 >> 2, ka1 = (c1 & 3) << 3;
    const __hip_bfloat16* pa0 = A + (size_t)(m0 + ra0) * K + ka0;
    const __hip_bfloat16* pa1 = A + (size_t)(m0 + ra1) * K + ka1;
    const __hip_bfloat16* pb0 = W + (size_t)(n0 + ra0) * K + ka0;
    const __hip_bfloat16* pb1 = W + (size_t)(n0 + ra1) * K + ka1;
    __hip_bfloat16* la0 = &As[c0 * 8];
    __hip_bfloat16* la1 = &As[c1 * 8];
    __hip_bfloat16* lb0 = &Bs[c0 * 8];
    __hip_bfloat16* lb1 = &Bs[c1 * 8];
    bool va0 = (m0 + ra0) < M, va1 = (m0 + ra1) < M;

    const short* Asp = (const short*)As + (wm + (lane & 15)) * 32 + (lane >> 4) * 8;
    const short* Bsp = (const short*)Bs + (wn + (lane & 15)) * 32 + (lane >> 4) * 8;

    float4v acc[4][4] = {};
    for (int kb = 0; kb < K; kb += 32) {
        if (va0) load_lds16(pa0, la0);
        if (va1) load_lds16(pa1, la1);
        load_lds16(pb0, lb0);
        load_lds16(pb1, lb1);
        pa0 += 32; pa1 += 32; pb0 += 32; pb1 += 32;
        __syncthreads();
        short8 a[4], b[4];
#pragma unroll
        for (int i = 0; i < 4; i++) a[i] = *(const short8*)(Asp + i * 512);
#pragma unroll
        for (int j = 0; j < 4; j++) b[j] = *(const short8*)(Bsp + j * 512);
#pragma unroll
        for (int i = 0; i < 4; i++)
#pragma unroll
            for (int j = 0; j < 4; j++)
                acc[i][j] = __builtin_amdgcn_mfma_f32_16x16x32_bf16(a[i], b[j], acc[i][j], 0, 0, 0);
        __syncthreads();
    }
    int rbase = m0 + wm + (lane >> 4) * 4;
    int cbase = n0 + wn + (lane & 15);
    float bi[4];
#pragma unroll
    for (int j = 0; j < 4; j++) bi[j] = bias[cbase + j * 16];
#pragma unroll
    for (int i = 0; i < 4; i++) {
#pragma unroll
        for (int r = 0; r < 4; r++) {
            int row = rbase + i * 16 + r;
            if (row >= M) continue;
#pragma unroll
            for (int j = 0; j < 4; j++) {
                int col = cbase + j * 16;
                float v = acc[i][j][r] + bi[j];
                if (EPI == 1) v = gelu_f(v);
                if (EPI == 2) v += res[(size_t)row * N + col];
                C[(size_t)row * N + col] = (CT)v;
            }
        }
    }
}

// 128x64 tile variant (4 waves as 2Mx2N, each 64x32) — for small grids (late layers).
template <int EPI, typename CT>
__global__ __launch_bounds__(256)
void gemm_mfma_n64(const __hip_bfloat16* __restrict__ A, const __hip_bfloat16* __restrict__ W,
                   const float* __restrict__ bias, const float* __restrict__ res,
                   CT* __restrict__ C, int M, int N, int K) {
    __shared__ __hip_bfloat16 As[128 * 32];
    __shared__ __hip_bfloat16 Bs[64 * 32];
    int tid = threadIdx.x;
    int lane = tid & 63;
    int wave = tid >> 6;
    int m0 = blockIdx.y * 128, n0 = blockIdx.x * 64;
    int wm = (wave >> 1) * 64, wn = (wave & 1) * 32;

    int c0 = tid, c1 = tid + 256;
    int ra0 = c0 >> 2, ka0 = (c0 & 3) << 3;
    int ra1 = c1 >> 2, ka1 = (c1 & 3) << 3;
    int rb  = tid >> 2, kb_ = (tid & 3) << 3;
    const __hip_bfloat16* pa0 = A + (size_t)(m0 + ra0) * K + ka0;
    const __hip_bfloat16* pa1 = A + (size_t)(m0 + ra1) * K + ka1;
    const __hip_bfloat16* pb  = W + (size_t)(n0 + rb) * K + kb_;
    __hip_bfloat16* la0 = &As[c0 * 8];
    __hip_bfloat16* la1 = &As[c1 * 8];
    __hip_bfloat16* lb  = &Bs[tid * 8];
    bool va0 = (m0 + ra0) < M, va1 = (m0 + ra1) < M;

    const short* Asp = (const short*)As + (wm + (lane & 15)) * 32 + (lane >> 4) * 8;
    const short* Bsp = (const short*)Bs + (wn + (lane & 15)) * 32 + (lane >> 4) * 8;

    float4v acc[4][2] = {};
    for (int kb = 0; kb < K; kb += 32) {
        if (va0) load_lds16(pa0, la0);
        if (va1) load_lds16(pa1, la1);
        load_lds16(pb, lb);
        pa0 += 32; pa1 += 32; pb += 32;
        __syncthreads();
        short8 a[4], b[2];
#pragma unroll
        for (int i = 0; i < 4; i++) a[i] = *(const short8*)(Asp + i * 512);
#pragma unroll
        for (int j = 0; j < 2; j++) b[j] = *(const short8*)(Bsp + j * 512);
#pragma unroll
        for (int i = 0; i < 4; i++)
#pragma unroll
            for (int j = 0; j < 2; j++)
                acc[i][j] = __builtin_amdgcn_mfma_f32_16x16x32_bf16(a[i], b[j], acc[i][j], 0, 0, 0);
        __syncthreads();
    }
    int rbase = m0 + wm + (lane >> 4) * 4;
    int cbase = n0 + wn + (lane & 15);
    float bi[2];
#pragma unroll
    for (int j = 0; j < 2; j++) bi[j] = bias[cbase + j * 16];
#pragma unroll
    for (int i = 0; i < 4; i++) {
#pragma unroll
        for (int r = 0; r < 4; r++) {
            int row = rbase + i * 16 + r;
            if (row >= M) continue;
#pragma unroll
            for (int j = 0; j < 2; j++) {
                int col = cbase + j * 16;
                float v = acc[i][j][r] + bi[j];
                if (EPI == 1) v = gelu_f(v);
                if (EPI == 2) v += res[(size_t)row * N + col];
                C[(size_t)row * N + col] = (CT)v;
            }
        }
    }
}

template <typename CT>
static inline void gemm_bf(hipStream_t st, const __hip_bfloat16* A, const __hip_bfloat16* W,
                           const float* bias, const float* res, CT* C,
                           int M, int N, int K, int epi) {
    long blocks128 = (long)(N / 128) * ((M + 127) / 128);
    if (blocks128 >= 160) {
        dim3 g(N / 128, (M + 127) / 128), b(256);
        if (epi == 0)      gemm_mfma<0, CT><<<g, b, 0, st>>>(A, W, bias, res, C, M, N, K);
        else if (epi == 1) gemm_mfma<1, CT><<<g, b, 0, st>>>(A, W, bias, res, C, M, N, K);
        else               gemm_mfma<2, CT><<<g, b, 0, st>>>(A, W, bias, res, C, M, N, K);
    } else {
        dim3 g(N / 64, (M + 127) / 128), b(256);
        if (epi == 0)      gemm_mfma_n64<0, CT><<<g, b, 0, st>>>(A, W, bias, res, C, M, N, K);
        else if (epi == 1) gemm_mfma_n64<1, CT><<<g, b, 0, st>>>(A, W, bias, res, C, M, N, K);
        else               gemm_mfma_n64<2, CT><<<g, b, 0, st>>>(A, W, bias, res, C, M, N, K);
    }
}

// ---------------- fp32 GEMM (small predictor/head mats) ----------------
template <int EPI>
__global__ __launch_bounds__(256)
void gemm_kernel(const float* __restrict__ A, const float* __restrict__ W,
                 const float* __restrict__ bias, const float* __restrict__ res,
                 float* __restrict__ C, int M, int N, int K) {
    __shared__ float As[16][128];
    __shared__ float Ws[16][64];
    int tid = threadIdx.x;
    int tx = tid & 15, ty = tid >> 4;
    int m0 = blockIdx.y * 128, n0 = blockIdx.x * 64;
    int arow = tid >> 1;
    int akh = (tid & 1) * 8;
    int brow = tid & 63;
    int bkq = (tid >> 6) * 4;
    const float* Arow = A + (size_t)(m0 + arow) * K;
    const float* Wrow = W + (size_t)(n0 + brow) * K;
    bool aval = (m0 + arow) < M;
    bool bval = (n0 + brow) < N;
    float acc[8][4] = {};
    for (int kb = 0; kb < K; kb += 16) {
        float4 av0 = make_float4(0.f, 0.f, 0.f, 0.f), av1 = av0, bv0 = av0;
        if (aval) {
            av0 = *(const float4*)(Arow + kb + akh);
            av1 = *(const float4*)(Arow + kb + akh + 4);
        }
        if (bval) bv0 = *(const float4*)(Wrow + kb + bkq);
        __syncthreads();
        As[akh + 0][arow] = av0.x; As[akh + 1][arow] = av0.y;
        As[akh + 2][arow] = av0.z; As[akh + 3][arow] = av0.w;
        As[akh + 4][arow] = av1.x; As[akh + 5][arow] = av1.y;
        As[akh + 6][arow] = av1.z; As[akh + 7][arow] = av1.w;
        Ws[bkq + 0][brow] = bv0.x; Ws[bkq + 1][brow] = bv0.y;
        Ws[bkq + 2][brow] = bv0.z; Ws[bkq + 3][brow] = bv0.w;
        __syncthreads();
#pragma unroll
        for (int kk = 0; kk < 16; kk++) {
            float4 a0 = *(const float4*)&As[kk][ty * 8];
            float4 a1 = *(const float4*)&As[kk][ty * 8 + 4];
            float4 b0 = *(const float4*)&Ws[kk][tx * 4];
            float a[8] = {a0.x, a0.y, a0.z, a0.w, a1.x, a1.y, a1.z, a1.w};
            float bb4[4] = {b0.x, b0.y, b0.z, b0.w};
#pragma unroll
            for (int i = 0; i < 8; i++)
#pragma unroll
                for (int j = 0; j < 4; j++) acc[i][j] += a[i] * bb4[j];
        }
    }
#pragma unroll
    for (int i = 0; i < 8; i++) {
        int m = m0 + ty * 8 + i;
        if (m >= M) break;
        int n = n0 + tx * 4;
        if (n >= N) continue;
        float4 v = make_float4(acc[i][0] + bias[n], acc[i][1] + bias[n + 1],
                               acc[i][2] + bias[n + 2], acc[i][3] + bias[n + 3]);
        if (EPI == 1) {
            v.x = gelu_f(v.x); v.y = gelu_f(v.y); v.z = gelu_f(v.z); v.w = gelu_f(v.w);
        }
        if (EPI == 2) {
            const float4 r = *(const float4*)(res + (size_t)m * N + n);
            v.x += r.x; v.y += r.y; v.z += r.z; v.w += r.w;
        }
        *(float4*)(C + (size_t)m * N + n) = v;
    }
}

static inline void gemm(hipStream_t st, const float* A, const float* W, const float* bias,
                        const float* res, float* C, int M, int N, int K, int epi) {
    dim3 g((N + 63) / 64, (M + 127) / 128), b(256);
    if (epi == 0)      gemm_kernel<0><<<g, b, 0, st>>>(A, W, bias, res, C, M, N, K);
    else if (epi == 1) gemm_kernel<1><<<g, b, 0, st>>>(A, W, bias, res, C, M, N, K);
    else               gemm_kernel<2><<<g, b, 0, st>>>(A, W, bias, res, C, M, N, K);
}

// ---------------- attention: block per (b,h,32-query tile), bf16 in/out ----------------
__global__ __launch_bounds__(256)
void attn_v2(const __hip_bfloat16* __restrict__ qkv, __hip_bfloat16* __restrict__ o, int L, int QT) {
    __shared__ float Qs[32][68];
    __shared__ float KVs[64][68];
    __shared__ float Ss[32][204];
    __shared__ float red8[256];
    __shared__ float rowstat[32];
    int tid = threadIdx.x;
    int idx = blockIdx.x;
    int qt = idx % QT; idx /= QT;
    int h = idx % NHEAD;
    int b = idx / NHEAD;
    int q0 = qt * 32;
    const __hip_bfloat16* base = qkv + (size_t)b * L * 2304 + h * 64;
    {
        int row = tid >> 3, dg = (tid & 7) * 8;
        float vals[8] = {};
        if ((q0 + row) < L) {
            short8 s = *(const short8*)(base + (size_t)(q0 + row) * 2304 + dg);
#pragma unroll
            for (int k2 = 0; k2 < 8; k2++) vals[k2] = bf2f(s[k2]);
        }
        *(float4*)&Qs[row][dg]     = make_float4(vals[0], vals[1], vals[2], vals[3]);
        *(float4*)&Qs[row][dg + 4] = make_float4(vals[4], vals[5], vals[6], vals[7]);
    }
    int nchunk = (L + 63) >> 6;
    int Lc4 = (L + 3) & ~3;
    {
        int qq = tid & 7;
        int jg = tid >> 3;
        for (int jc = 0; jc < nchunk; jc++) {
            __syncthreads();
            {
                int row = tid >> 2, dg = (tid & 3) * 16;
                int j = jc * 64 + row;
                float vals[16] = {};
                if (j < L) {
                    const __hip_bfloat16* src = base + (size_t)j * 2304 + 768 + dg;
                    short8 s0 = *(const short8*)(src);
                    short8 s1 = *(const short8*)(src + 8);
#pragma unroll
                    for (int k2 = 0; k2 < 8; k2++) { vals[k2] = bf2f(s0[k2]); vals[8 + k2] = bf2f(s1[k2]); }
                }
                *(float4*)&KVs[row][dg]      = make_float4(vals[0], vals[1], vals[2], vals[3]);
                *(float4*)&KVs[row][dg + 4]  = make_float4(vals[4], vals[5], vals[6], vals[7]);
                *(float4*)&KVs[row][dg + 8]  = make_float4(vals[8], vals[9], vals[10], vals[11]);
                *(float4*)&KVs[row][dg + 12] = make_float4(vals[12], vals[13], vals[14], vals[15]);
            }
            __syncthreads();
            float sacc[4][2] = {};
#pragma unroll 4
            for (int d4 = 0; d4 < 64; d4 += 4) {
                float4 qa[4], ka[2];
#pragma unroll
                for (int qi = 0; qi < 4; qi++) qa[qi] = *(const float4*)&Qs[qq + 8 * qi][d4];
#pragma unroll
                for (int ji = 0; ji < 2; ji++) ka[ji] = *(const float4*)&KVs[jg + 32 * ji][d4];
#pragma unroll
                for (int qi = 0; qi < 4; qi++)
#pragma unroll
                    for (int ji = 0; ji < 2; ji++) sacc[qi][ji] += dot4(qa[qi], ka[ji]);
            }
#pragma unroll
            for (int qi = 0; qi < 4; qi++)
#pragma unroll
                for (int ji = 0; ji < 2; ji++) {
                    int j = jc * 64 + jg + 32 * ji;
                    float sv = (j < L) ? sacc[qi][ji] * ATT_SCALE : 0.f;
                    if (j < Lc4) Ss[qq + 8 * qi][j] = sv;
                }
        }
    }
    __syncthreads();
    {
        int q = tid & 31, c = tid >> 5;
        float mx = -1e30f;
        for (int j = c; j < L; j += 8) mx = fmaxf(mx, Ss[q][j]);
        red8[c * 32 + q] = mx;
        __syncthreads();
        if (tid < 32) {
            float m2 = red8[tid];
#pragma unroll
            for (int cc = 1; cc < 8; cc++) m2 = fmaxf(m2, red8[cc * 32 + tid]);
            rowstat[tid] = m2;
        }
        __syncthreads();
        mx = rowstat[q];
        float sm = 0.f;
        for (int j = c; j < L; j += 8) {
            float e = __expf(Ss[q][j] - mx);
            Ss[q][j] = e;
            sm += e;
        }
        red8[c * 32 + q] = sm;
        __syncthreads();
        if (tid < 32) {
            float s2 = red8[tid];
#pragma unroll
            for (int cc = 1; cc < 8; cc++) s2 += red8[cc * 32 + tid];
            rowstat[tid] = 1.0f / s2;
        }
    }
    int qq2 = tid & 15, g4 = (tid >> 4) * 4;
    float O[2][4] = {};
    for (int jc = 0; jc < nchunk; jc++) {
        __syncthreads();
        {
            int row = tid >> 2, dg = (tid & 3) * 16;
            int j = jc * 64 + row;
            float vals[16] = {};
            if (j < L) {
                const __hip_bfloat16* src = base + (size_t)j * 2304 + 1536 + dg;
                short8 s0 = *(const short8*)(src);
                short8 s1 = *(const short8*)(src + 8);
#pragma unroll
                for (int k2 = 0; k2 < 8; k2++) { vals[k2] = bf2f(s0[k2]); vals[8 + k2] = bf2f(s1[k2]); }
            }
            *(float4*)&KVs[row][dg]      = make_float4(vals[0], vals[1], vals[2], vals[3]);
            *(float4*)&KVs[row][dg + 4]  = make_float4(vals[4], vals[5], vals[6], vals[7]);
            *(float4*)&KVs[row][dg + 8]  = make_float4(vals[8], vals[9], vals[10], vals[11]);
            *(float4*)&KVs[row][dg + 12] = make_float4(vals[12], vals[13], vals[14], vals[15]);
        }
        __syncthreads();
        int jmax = min(64, L - jc * 64);
        for (int j4 = 0; j4 < jmax; j4 += 4) {
            float4 p0 = *(const float4*)&Ss[qq2][jc * 64 + j4];
            float4 p1 = *(const float4*)&Ss[qq2 + 16][jc * 64 + j4];
            float pa0[4] = {p0.x, p0.y, p0.z, p0.w};
            float pa1[4] = {p1.x, p1.y, p1.z, p1.w};
#pragma unroll
            for (int jj = 0; jj < 4; jj++) {
                float4 kv = *(const float4*)&KVs[j4 + jj][g4];
                O[0][0] += pa0[jj] * kv.x; O[0][1] += pa0[jj] * kv.y;
                O[0][2] += pa0[jj] * kv.z; O[0][3] += pa0[jj] * kv.w;
                O[1][0] += pa1[jj] * kv.x; O[1][1] += pa1[jj] * kv.y;
                O[1][2] += pa1[jj] * kv.z; O[1][3] += pa1[jj] * kv.w;
            }
        }
    }
#pragma unroll
    for (int qi = 0; qi < 2; qi++) {
        int q = qq2 + 16 * qi;
        if (q0 + q < L) {
            float inv = rowstat[q];
            __hip_bfloat16* op = o + ((size_t)(b * L + q0 + q)) * 768 + h * 64 + g4;
            op[0] = __float2bfloat16(O[qi][0] * inv);
            op[1] = __float2bfloat16(O[qi][1] * inv);
            op[2] = __float2bfloat16(O[qi][2] * inv);
            op[3] = __float2bfloat16(O[qi][3] * inv);
        }
    }
}

// ---------------- predictor helpers ----------------
__global__ void globmean_kernel(const float* __restrict__ hp, float* __restrict__ glob, int Lc) {
    int b = blockIdx.x;
    int c = threadIdx.x;
    float s = 0.f;
    for (int l = 0; l < Lc; l++) s += hp[((size_t)(b * Lc + l)) * 768 + 384 + c];
    glob[b * 384 + c] = s / (float)Lc;
}

__global__ void globbcast_kernel(float* __restrict__ hp, const float* __restrict__ glob, int Lc) {
    int row = blockIdx.x;
    int b = row / Lc;
    int c = threadIdx.x;
    hp[(size_t)row * 768 + 384 + c] = glob[b * 384 + c];
}

__global__ __launch_bounds__(256)
void score_kernel(const float* __restrict__ p2, const float* __restrict__ w3,
                  const float* __restrict__ b3, float* __restrict__ score) {
    __shared__ float red[256];
    int row = blockIdx.x;
    int tid = threadIdx.x;
    red[tid] = (tid < 192) ? p2[(size_t)row * 192 + tid] * w3[tid] : 0.f;
    __syncthreads();
    for (int st = 128; st > 0; st >>= 1) {
        if (tid < st) red[tid] += red[tid + st];
        __syncthreads();
    }
    if (tid == 0) {
        float x = red[0] + b3[0];
        score[row] = fminf(x, 0.0f) - log1pf(__expf(-fabsf(x)));
    }
}

// ---------------- top-k (set-equivalent to jax.lax.top_k) ----------------
__global__ void topk_kernel(const float* __restrict__ score, int* __restrict__ kidx,
                            int Lc, int k) {
    __shared__ float s[196];
    __shared__ int keep[196];
    int b = blockIdx.x, tid = threadIdx.x;
    for (int i = tid; i < Lc; i += 256) s[i] = score[b * Lc + i];
    __syncthreads();
    for (int i = tid; i < Lc; i += 256) {
        float si = s[i];
        int rank = 0;
        for (int j = 0; j < Lc; j++) {
            float sj = s[j];
            rank += (sj > si) || (sj == si && j < i);
        }
        keep[i] = (rank < k) ? 1 : 0;
    }
    __syncthreads();
    for (int i = tid; i < Lc; i += 256) {
        if (keep[i]) {
            int pos = 0;
            for (int j = 0; j < i; j++) pos += keep[j];
            kidx[b * MAXK + pos] = i;
        }
    }
}

__global__ void gather_kernel(const float* __restrict__ t, const int* __restrict__ kidx,
                              float* __restrict__ dst, int L, int Lnew) {
    int row = blockIdx.x;
    int b = row / Lnew, m = row % Lnew;
    int srcrow = (m == 0) ? b * L : b * L + 1 + kidx[b * MAXK + m - 1];
    const float* sp = t + (size_t)srcrow * 768;
    float* dp = dst + (size_t)row * 768;
    for (int c = threadIdx.x; c < 768; c += 256) dp[c] = sp[c];
}

// ---------------- host orchestration ----------------
extern "C" void kernel_launch(void* const* d_in, const int* in_sizes, int n_in,
                              void* d_out, int out_size, void* d_ws, size_t ws_size,
                              hipStream_t stream) {
    const float* x        = (const float*)d_in[0];
    const float* patch_w  = (const float*)d_in[1];
    const float* patch_b  = (const float*)d_in[2];
    const float* cls_tok  = (const float*)d_in[3];
    const float* pos_emb  = (const float*)d_in[4];
    const float* ln1_g    = (const float*)d_in[5];
    const float* ln1_b    = (const float*)d_in[6];
    const float* qkv_w    = (const float*)d_in[7];
    const float* qkv_b    = (const float*)d_in[8];
    const float* proj_w   = (const float*)d_in[9];
    const float* proj_b   = (const float*)d_in[10];
    const float* ln2_g    = (const float*)d_in[11];
    const float* ln2_b    = (const float*)d_in[12];
    const float* fc1_w    = (const float*)d_in[13];
    const float* fc1_b    = (const float*)d_in[14];
    const float* fc2_w    = (const float*)d_in[15];
    const float* fc2_b    = (const float*)d_in[16];
    const float* pln_g    = (const float*)d_in[17];
    const float* pln_b    = (const float*)d_in[18];
    const float* pin_w    = (const float*)d_in[19];
    const float* pin_b    = (const float*)d_in[20];
    const float* pw1      = (const float*)d_in[21];
    const float* pb1      = (const float*)d_in[22];
    const float* pw2      = (const float*)d_in[23];
    const float* pb2      = (const float*)d_in[24];
    const float* pw3      = (const float*)d_in[25];
    const float* pb3      = (const float*)d_in[26];
    const float* norm_g   = (const float*)d_in[27];
    const float* norm_b   = (const float*)d_in[28];
    const float* head_w   = (const float*)d_in[29];
    const float* head_b   = (const float*)d_in[30];

    float* ws = (float*)d_ws;
    float* cur   = ws + OFF_T0;
    float* tmp   = ws + OFF_T1;
    float* C32   = ws + OFF_C32;
    __hip_bfloat16* ABF = (__hip_bfloat16*)(ws + OFF_ABF);
    __hip_bfloat16* WL  = (__hip_bfloat16*)(ws + OFF_WL);
    __hip_bfloat16* QBF = (__hip_bfloat16*)C32;  // qkv bf16 out overlays C32 region
    __hip_bfloat16* BBF = (__hip_bfloat16*)C32;  // fc1 bf16 out overlays C32 region
    float* GLOB  = ws + OFF_GLOB;
    float* SCORE = ws + OFF_SCORE;
    int*   KIDX  = (int*)(ws + OFF_KIDX);
    float* CLS   = ws + OFF_CLS;

    // patch embed
    cvt(stream, patch_w, WL, 768 * 768);
    patch_kernel<<<(BATCH * 196 * 768) / 256, 256, 0, stream>>>(x, ABF);
    gemm_bf<float>(stream, ABF, WL, patch_b, nullptr, C32, BATCH * 196, 768, 768, 0);
    assemble_kernel<<<BATCH * 197, 256, 0, stream>>>(C32, cls_tok, pos_emb, cur);

    int L = 197;
    for (int i = 0; i < DEPTH; i++) {
        bool isprune = (i == 3 || i == 6 || i == 9);
        // fused per-layer weight conversion (single launch)
        {
            int nblk = isprune ? 3744 : 3456;   // (7,667,712 or 7,077,888) / 8 / 256
            const float* pin_src = isprune ? pin_w + (size_t)(i / 3 - 1) * 768 * 768 : qkv_w;
            cvt_layer_kernel<<<nblk, 256, 0, stream>>>(
                qkv_w + (size_t)i * 2304 * 768, proj_w + (size_t)i * 768 * 768,
                fc1_w + (size_t)i * 3072 * 768, fc2_w + (size_t)i * 768 * 3072,
                pin_src, WL);
        }
        if (isprune) {
            int s = i / 3 - 1;
            int Lc = L - 1;
            int k = (7 * Lc + 9) / 10;  // ceil(0.7*Lc)
            ln_kernel<__hip_bfloat16><<<BATCH * Lc, 256, 0, stream>>>(
                cur, ABF, pln_g + s * 768, pln_b + s * 768, Lc, L, 1, Lc, 0);
            gemm_bf<float>(stream, ABF, WL + W_PIN, pin_b + s * 768, nullptr, C32,
                           BATCH * Lc, 768, 768, 1);
            globmean_kernel<<<BATCH, 384, 0, stream>>>(C32, GLOB, Lc);
            globbcast_kernel<<<BATCH * Lc, 384, 0, stream>>>(C32, GLOB, Lc);
            gemm(stream, C32, pw1 + (size_t)s * 384 * 768, pb1 + s * 384, nullptr, tmp,
                 BATCH * Lc, 384, 768, 1);
            float* P2 = tmp + 2500000;
            gemm(stream, tmp, pw2 + (size_t)s * 192 * 384, pb2 + s * 192, nullptr, P2,
                 BATCH * Lc, 192, 384, 1);
            score_kernel<<<BATCH * Lc, 256, 0, stream>>>(P2, pw3 + s * 192, pb3 + s, SCORE);
            topk_kernel<<<BATCH, 256, 0, stream>>>(SCORE, KIDX, Lc, k);
            int Lnew = k + 1;
            gather_kernel<<<BATCH * Lnew, 256, 0, stream>>>(cur, KIDX, tmp, L, Lnew);
            float* t_ = cur; cur = tmp; tmp = t_;
            L = Lnew;
        }
        int M = BATCH * L;
        int QT = (L + 31) / 32;
        // attention
        ln_kernel<__hip_bfloat16><<<M, 256, 0, stream>>>(
            cur, ABF, ln1_g + i * 768, ln1_b + i * 768, L, L, 0, L, 0);
        gemm_bf<__hip_bfloat16>(stream, ABF, WL + W_QKV, qkv_b + i * 2304, nullptr, QBF,
                                M, 2304, 768, 0);
        attn_v2<<<BATCH * NHEAD * QT, 256, 0, stream>>>(QBF, ABF, L, QT);
        gemm_bf<float>(stream, ABF, WL + W_PROJ, proj_b + i * 768, cur, cur, M, 768, 768, 2);
        // MLP
        ln_kernel<__hip_bfloat16><<<M, 256, 0, stream>>>(
            cur, ABF, ln2_g + i * 768, ln2_b + i * 768, L, L, 0, L, 0);
        gemm_bf<__hip_bfloat16>(stream, ABF, WL + W_FC1, fc1_b + i * 3072, nullptr, BBF,
                                M, 3072, 768, 1);
        gemm_bf<float>(stream, BBF, WL + W_FC2, fc2_b + i * 768, cur, cur, M, 768, 3072, 2);
    }
    ln_kernel<float><<<BATCH, 256, 0, stream>>>(cur, CLS, norm_g, norm_b, 1, L, 0, 1, 0);
    gemm(stream, CLS, head_w, head_b, nullptr, (float*)d_out, BATCH, 1000, 768, 0);
}

// Round 2
// 3815.086 us; speedup vs baseline: 1.0811x; 1.0811x over previous
//
#include <hip/hip_runtime.h>
#include <hip/hip_bf16.h>
#include <math.h>

// ---------------- model constants ----------------
constexpr int BATCH = 32;
constexpr int NHEAD = 12;
constexpr int DEPTH = 12;
constexpr int L0TOK = 196;
constexpr int MAXK = 138;
constexpr float ATT_SCALE = 0.125f;

// workspace layout (float-slot offsets)
constexpr size_t SZ_T = (size_t)BATCH * 197 * 768;            // 4,841,472
constexpr size_t OFF_T0 = 0;
constexpr size_t OFF_T1 = SZ_T;
constexpr size_t OFF_C32 = 2 * SZ_T;                          // 14,524,416 floats
constexpr size_t OFF_ABF = OFF_C32 + (size_t)BATCH * 197 * 2304;   // bf16 activations (2,420,736 slots)
constexpr size_t OFF_WL  = OFF_ABF + 2420736;                 // bf16 weights: 7,667,712 bf16 = 3,833,856 float slots
constexpr size_t OFF_GLOB  = OFF_WL + 3833856;
constexpr size_t OFF_SCORE = OFF_GLOB + (size_t)BATCH * 384;
constexpr size_t OFF_KIDX  = OFF_SCORE + (size_t)BATCH * L0TOK;
constexpr size_t OFF_CLS   = OFF_KIDX + (size_t)BATCH * 140;

// per-layer bf16 weight sub-offsets (bf16-element units)
constexpr size_t W_QKV  = 0;               // 2304*768 = 1,769,472
constexpr size_t W_PROJ = 1769472;         // 768*768  =   589,824
constexpr size_t W_FC1  = 2359296;         // 3072*768 = 2,359,296
constexpr size_t W_FC2  = 4718592;         // 768*3072 = 2,359,296
constexpr size_t W_PIN  = 7077888;         // 768*768  =   589,824

typedef __attribute__((ext_vector_type(8))) short short8;
typedef __attribute__((ext_vector_type(4))) float float4v;

__device__ __forceinline__ float gelu_f(float x) {
    return 0.5f * x * (1.0f + erff(x * 0.7071067811865476f));
}

// async 16B global->LDS (DMA, no VGPR round trip)
__device__ __forceinline__ void load_lds16(const void* g, void* l) {
    __builtin_amdgcn_global_load_lds(
        (const __attribute__((address_space(1))) unsigned int*)g,
        (__attribute__((address_space(3))) unsigned int*)l, 16, 0, 0);
}

// ---------------- fp32 -> bf16 weight conversion ----------------
__global__ void cvt_kernel(const float* __restrict__ src, __hip_bfloat16* __restrict__ dst, int n) {
    int i = (blockIdx.x * 256 + threadIdx.x) * 4;
    if (i >= n) return;
    float4 v = *(const float4*)(src + i);
    dst[i + 0] = __float2bfloat16(v.x);
    dst[i + 1] = __float2bfloat16(v.y);
    dst[i + 2] = __float2bfloat16(v.z);
    dst[i + 3] = __float2bfloat16(v.w);
}
static inline void cvt(hipStream_t st, const float* s, __hip_bfloat16* d, size_t n) {
    cvt_kernel<<<(n / 4 + 255) / 256, 256, 0, st>>>(s, d, (int)n);
}

// fused per-layer weight convert: qkv|proj|fc1|fc2[|pin] in one launch.
__global__ void cvt_layer_kernel(const float* __restrict__ wqkv, const float* __restrict__ wproj,
                                 const float* __restrict__ wfc1, const float* __restrict__ wfc2,
                                 const float* __restrict__ wpin, __hip_bfloat16* __restrict__ dst) {
    size_t i = ((size_t)blockIdx.x * 256 + threadIdx.x) * 8;
    const float* src;
    size_t off;
    if (i < W_PROJ)      { src = wqkv;  off = i; }
    else if (i < W_FC1)  { src = wproj; off = i - W_PROJ; }
    else if (i < W_FC2)  { src = wfc1;  off = i - W_FC1; }
    else if (i < W_PIN)  { src = wfc2;  off = i - W_FC2; }
    else                 { src = wpin;  off = i - W_PIN; }
    float4 a = *(const float4*)(src + off);
    float4 b = *(const float4*)(src + off + 4);
    union { short8 v; __hip_bfloat16 h[8]; } u;
    u.h[0] = __float2bfloat16(a.x); u.h[1] = __float2bfloat16(a.y);
    u.h[2] = __float2bfloat16(a.z); u.h[3] = __float2bfloat16(a.w);
    u.h[4] = __float2bfloat16(b.x); u.h[5] = __float2bfloat16(b.y);
    u.h[6] = __float2bfloat16(b.z); u.h[7] = __float2bfloat16(b.w);
    *(short8*)(dst + i) = u.v;
}

// ---------------- patch rearrange (bf16 out) ----------------
__global__ void patch_kernel(const float* __restrict__ x, __hip_bfloat16* __restrict__ p) {
    int idx = blockIdx.x * 256 + threadIdx.x;
    int c = idx % 768;
    int rest = idx / 768;
    int l = rest % 196;
    int b = rest / 196;
    int ch = c >> 8;
    int py = (c & 255) >> 4;
    int px = c & 15;
    int gy = l / 14, gx = l % 14;
    p[idx] = __float2bfloat16(
        x[(((size_t)b * 3 + ch) * 224 + gy * 16 + py) * 224 + gx * 16 + px]);
}

// ---------------- assemble t = [cls; patches] + pos (fp32) ----------------
__global__ void assemble_kernel(const float* __restrict__ pe, const float* __restrict__ cls,
                                const float* __restrict__ pos, float* __restrict__ t) {
    int row = blockIdx.x;
    int b = row / 197, l = row % 197;
    for (int c = threadIdx.x; c < 768; c += 256) {
        float v = (l == 0) ? cls[c] : pe[((size_t)(b * 196 + l - 1)) * 768 + c];
        t[(size_t)row * 768 + c] = v + pos[l * 768 + c];
    }
}

// ---------------- layernorm, templated output type ----------------
template <typename OT>
__global__ __launch_bounds__(256)
void ln_kernel(const float* __restrict__ src, OT* __restrict__ dst,
               const float* __restrict__ g, const float* __restrict__ bb,
               int R, int SB, int SO, int DB, int DO_) {
    __shared__ float red[256];
    int row = blockIdx.x;
    int b = row / R, r = row % R;
    const float* sp = src + ((size_t)b * SB + SO + r) * 768;
    OT* dp = dst + ((size_t)b * DB + DO_ + r) * 768;
    int tid = threadIdx.x;
    float x0 = sp[tid], x1 = sp[tid + 256], x2 = sp[tid + 512];
    red[tid] = x0 + x1 + x2;
    __syncthreads();
    for (int st = 128; st > 0; st >>= 1) {
        if (tid < st) red[tid] += red[tid + st];
        __syncthreads();
    }
    float mean = red[0] * (1.0f / 768.0f);
    __syncthreads();
    float d0 = x0 - mean, d1 = x1 - mean, d2 = x2 - mean;
    red[tid] = d0 * d0 + d1 * d1 + d2 * d2;
    __syncthreads();
    for (int st = 128; st > 0; st >>= 1) {
        if (tid < st) red[tid] += red[tid + st];
        __syncthreads();
    }
    float inv = rsqrtf(red[0] * (1.0f / 768.0f) + 1e-6f);
    dp[tid]       = (OT)(d0 * inv * g[tid]       + bb[tid]);
    dp[tid + 256] = (OT)(d1 * inv * g[tid + 256] + bb[tid + 256]);
    dp[tid + 512] = (OT)(d2 * inv * g[tid + 512] + bb[tid + 512]);
}

// ---------------- MFMA GEMM: C = A(MxK,bf16) @ W(NxK,bf16)^T + bias ----------------
template <int EPI, typename CT>
__global__ __launch_bounds__(256)
void gemm_mfma(const __hip_bfloat16* __restrict__ A, const __hip_bfloat16* __restrict__ W,
               const float* __restrict__ bias, const float* __restrict__ res,
               CT* __restrict__ C, int M, int N, int K) {
    __shared__ __hip_bfloat16 As[128 * 32];
    __shared__ __hip_bfloat16 Bs[128 * 32];
    int tid = threadIdx.x;
    int lane = tid & 63;
    int wave = tid >> 6;
    int m0 = blockIdx.y * 128, n0 = blockIdx.x * 128;
    int wm = (wave >> 1) * 64, wn = (wave & 1) * 64;

    int c0 = tid, c1 = tid + 256;
    int ra0 = c0 >> 2, ka0 = (c0 & 3) << 3;
    int ra1 = c1 >> 2, ka1 = (c1 & 3) << 3;
    const __hip_bfloat16* pa0 = A + (size_t)(m0 + ra0) * K + ka0;
    const __hip_bfloat16* pa1 = A + (size_t)(m0 + ra1) * K + ka1;
    const __hip_bfloat16* pb0 = W + (size_t)(n0 + ra0) * K + ka0;
    const __hip_bfloat16* pb1 = W + (size_t)(n0 + ra1) * K + ka1;
    __hip_bfloat16* la0 = &As[c0 * 8];
    __hip_bfloat16* la1 = &As[c1 * 8];
    __hip_bfloat16* lb0 = &Bs[c0 * 8];
    __hip_bfloat16* lb1 = &Bs[c1 * 8];
    bool va0 = (m0 + ra0) < M, va1 = (m0 + ra1) < M;

    const short* Asp = (const short*)As + (wm + (lane & 15)) * 32 + (lane >> 4) * 8;
    const short* Bsp = (const short*)Bs + (wn + (lane & 15)) * 32 + (lane >> 4) * 8;

    float4v acc[4][4] = {};
    for (int kb = 0; kb < K; kb += 32) {
        if (va0) load_lds16(pa0, la0);
        if (va1) load_lds16(pa1, la1);
        load_lds16(pb0, lb0);
        load_lds16(pb1, lb1);
        pa0 += 32; pa1 += 32; pb0 += 32; pb1 += 32;
        __syncthreads();
        short8 a[4], b[4];
#pragma unroll
        for (int i = 0; i < 4; i++) a[i] = *(const short8*)(Asp + i * 512);
#pragma unroll
        for (int j = 0; j < 4; j++) b[j] = *(const short8*)(Bsp + j * 512);
#pragma unroll
        for (int i = 0; i < 4; i++)
#pragma unroll
            for (int j = 0; j < 4; j++)
                acc[i][j] = __builtin_amdgcn_mfma_f32_16x16x32_bf16(a[i], b[j], acc[i][j], 0, 0, 0);
        __syncthreads();
    }
    int rbase = m0 + wm + (lane >> 4) * 4;
    int cbase = n0 + wn + (lane & 15);
    float bi[4];
#pragma unroll
    for (int j = 0; j < 4; j++) bi[j] = bias[cbase + j * 16];
#pragma unroll
    for (int i = 0; i < 4; i++) {
#pragma unroll
        for (int r = 0; r < 4; r++) {
            int row = rbase + i * 16 + r;
            if (row >= M) continue;
#pragma unroll
            for (int j = 0; j < 4; j++) {
                int col = cbase + j * 16;
                float v = acc[i][j][r] + bi[j];
                if (EPI == 1) v = gelu_f(v);
                if (EPI == 2) v += res[(size_t)row * N + col];
                C[(size_t)row * N + col] = (CT)v;
            }
        }
    }
}

// 128x64 tile variant — for small grids (late layers).
template <int EPI, typename CT>
__global__ __launch_bounds__(256)
void gemm_mfma_n64(const __hip_bfloat16* __restrict__ A, const __hip_bfloat16* __restrict__ W,
                   const float* __restrict__ bias, const float* __restrict__ res,
                   CT* __restrict__ C, int M, int N, int K) {
    __shared__ __hip_bfloat16 As[128 * 32];
    __shared__ __hip_bfloat16 Bs[64 * 32];
    int tid = threadIdx.x;
    int lane = tid & 63;
    int wave = tid >> 6;
    int m0 = blockIdx.y * 128, n0 = blockIdx.x * 64;
    int wm = (wave >> 1) * 64, wn = (wave & 1) * 32;

    int c0 = tid, c1 = tid + 256;
    int ra0 = c0 >> 2, ka0 = (c0 & 3) << 3;
    int ra1 = c1 >> 2, ka1 = (c1 & 3) << 3;
    int rb  = tid >> 2, kb_ = (tid & 3) << 3;
    const __hip_bfloat16* pa0 = A + (size_t)(m0 + ra0) * K + ka0;
    const __hip_bfloat16* pa1 = A + (size_t)(m0 + ra1) * K + ka1;
    const __hip_bfloat16* pb  = W + (size_t)(n0 + rb) * K + kb_;
    __hip_bfloat16* la0 = &As[c0 * 8];
    __hip_bfloat16* la1 = &As[c1 * 8];
    __hip_bfloat16* lb  = &Bs[tid * 8];
    bool va0 = (m0 + ra0) < M, va1 = (m0 + ra1) < M;

    const short* Asp = (const short*)As + (wm + (lane & 15)) * 32 + (lane >> 4) * 8;
    const short* Bsp = (const short*)Bs + (wn + (lane & 15)) * 32 + (lane >> 4) * 8;

    float4v acc[4][2] = {};
    for (int kb = 0; kb < K; kb += 32) {
        if (va0) load_lds16(pa0, la0);
        if (va1) load_lds16(pa1, la1);
        load_lds16(pb, lb);
        pa0 += 32; pa1 += 32; pb += 32;
        __syncthreads();
        short8 a[4], b[2];
#pragma unroll
        for (int i = 0; i < 4; i++) a[i] = *(const short8*)(Asp + i * 512);
#pragma unroll
        for (int j = 0; j < 2; j++) b[j] = *(const short8*)(Bsp + j * 512);
#pragma unroll
        for (int i = 0; i < 4; i++)
#pragma unroll
            for (int j = 0; j < 2; j++)
                acc[i][j] = __builtin_amdgcn_mfma_f32_16x16x32_bf16(a[i], b[j], acc[i][j], 0, 0, 0);
        __syncthreads();
    }
    int rbase = m0 + wm + (lane >> 4) * 4;
    int cbase = n0 + wn + (lane & 15);
    float bi[2];
#pragma unroll
    for (int j = 0; j < 2; j++) bi[j] = bias[cbase + j * 16];
#pragma unroll
    for (int i = 0; i < 4; i++) {
#pragma unroll
        for (int r = 0; r < 4; r++) {
            int row = rbase + i * 16 + r;
            if (row >= M) continue;
#pragma unroll
            for (int j = 0; j < 2; j++) {
                int col = cbase + j * 16;
                float v = acc[i][j][r] + bi[j];
                if (EPI == 1) v = gelu_f(v);
                if (EPI == 2) v += res[(size_t)row * N + col];
                C[(size_t)row * N + col] = (CT)v;
            }
        }
    }
}

template <typename CT>
static inline void gemm_bf(hipStream_t st, const __hip_bfloat16* A, const __hip_bfloat16* W,
                           const float* bias, const float* res, CT* C,
                           int M, int N, int K, int epi) {
    long blocks128 = (long)(N / 128) * ((M + 127) / 128);
    if (blocks128 >= 160) {
        dim3 g(N / 128, (M + 127) / 128), b(256);
        if (epi == 0)      gemm_mfma<0, CT><<<g, b, 0, st>>>(A, W, bias, res, C, M, N, K);
        else if (epi == 1) gemm_mfma<1, CT><<<g, b, 0, st>>>(A, W, bias, res, C, M, N, K);
        else               gemm_mfma<2, CT><<<g, b, 0, st>>>(A, W, bias, res, C, M, N, K);
    } else {
        dim3 g(N / 64, (M + 127) / 128), b(256);
        if (epi == 0)      gemm_mfma_n64<0, CT><<<g, b, 0, st>>>(A, W, bias, res, C, M, N, K);
        else if (epi == 1) gemm_mfma_n64<1, CT><<<g, b, 0, st>>>(A, W, bias, res, C, M, N, K);
        else               gemm_mfma_n64<2, CT><<<g, b, 0, st>>>(A, W, bias, res, C, M, N, K);
    }
}

// ---------------- fp32 GEMM (small predictor/head mats) ----------------
template <int EPI>
__global__ __launch_bounds__(256)
void gemm_kernel(const float* __restrict__ A, const float* __restrict__ W,
                 const float* __restrict__ bias, const float* __restrict__ res,
                 float* __restrict__ C, int M, int N, int K) {
    __shared__ float As[16][128];
    __shared__ float Ws[16][64];
    int tid = threadIdx.x;
    int tx = tid & 15, ty = tid >> 4;
    int m0 = blockIdx.y * 128, n0 = blockIdx.x * 64;
    int arow = tid >> 1;
    int akh = (tid & 1) * 8;
    int brow = tid & 63;
    int bkq = (tid >> 6) * 4;
    const float* Arow = A + (size_t)(m0 + arow) * K;
    const float* Wrow = W + (size_t)(n0 + brow) * K;
    bool aval = (m0 + arow) < M;
    bool bval = (n0 + brow) < N;
    float acc[8][4] = {};
    for (int kb = 0; kb < K; kb += 16) {
        float4 av0 = make_float4(0.f, 0.f, 0.f, 0.f), av1 = av0, bv0 = av0;
        if (aval) {
            av0 = *(const float4*)(Arow + kb + akh);
            av1 = *(const float4*)(Arow + kb + akh + 4);
        }
        if (bval) bv0 = *(const float4*)(Wrow + kb + bkq);
        __syncthreads();
        As[akh + 0][arow] = av0.x; As[akh + 1][arow] = av0.y;
        As[akh + 2][arow] = av0.z; As[akh + 3][arow] = av0.w;
        As[akh + 4][arow] = av1.x; As[akh + 5][arow] = av1.y;
        As[akh + 6][arow] = av1.z; As[akh + 7][arow] = av1.w;
        Ws[bkq + 0][brow] = bv0.x; Ws[bkq + 1][brow] = bv0.y;
        Ws[bkq + 2][brow] = bv0.z; Ws[bkq + 3][brow] = bv0.w;
        __syncthreads();
#pragma unroll
        for (int kk = 0; kk < 16; kk++) {
            float4 a0 = *(const float4*)&As[kk][ty * 8];
            float4 a1 = *(const float4*)&As[kk][ty * 8 + 4];
            float4 b0 = *(const float4*)&Ws[kk][tx * 4];
            float a[8] = {a0.x, a0.y, a0.z, a0.w, a1.x, a1.y, a1.z, a1.w};
            float bb4[4] = {b0.x, b0.y, b0.z, b0.w};
#pragma unroll
            for (int i = 0; i < 8; i++)
#pragma unroll
                for (int j = 0; j < 4; j++) acc[i][j] += a[i] * bb4[j];
        }
    }
#pragma unroll
    for (int i = 0; i < 8; i++) {
        int m = m0 + ty * 8 + i;
        if (m >= M) break;
        int n = n0 + tx * 4;
        if (n >= N) continue;
        float4 v = make_float4(acc[i][0] + bias[n], acc[i][1] + bias[n + 1],
                               acc[i][2] + bias[n + 2], acc[i][3] + bias[n + 3]);
        if (EPI == 1) {
            v.x = gelu_f(v.x); v.y = gelu_f(v.y); v.z = gelu_f(v.z); v.w = gelu_f(v.w);
        }
        if (EPI == 2) {
            const float4 r = *(const float4*)(res + (size_t)m * N + n);
            v.x += r.x; v.y += r.y; v.z += r.z; v.w += r.w;
        }
        *(float4*)(C + (size_t)m * N + n) = v;
    }
}

static inline void gemm(hipStream_t st, const float* A, const float* W, const float* bias,
                        const float* res, float* C, int M, int N, int K, int epi) {
    dim3 g((N + 63) / 64, (M + 127) / 128), b(256);
    if (epi == 0)      gemm_kernel<0><<<g, b, 0, st>>>(A, W, bias, res, C, M, N, K);
    else if (epi == 1) gemm_kernel<1><<<g, b, 0, st>>>(A, W, bias, res, C, M, N, K);
    else               gemm_kernel<2><<<g, b, 0, st>>>(A, W, bias, res, C, M, N, K);
}

// ---------------- MFMA attention: block per (b,h,32-query tile), bf16 in/out ----------
// QK^T and PV on the matrix pipe (16x16x32 bf16). 4 waves: wave w owns 16 keys (QK)
// or 16 output dims (PV). LDS strides chosen conflict-free:
//   Qs/Ks/Vt stride 72 elems (144 B = 9*16B, odd multiple) for b128 frag reads
//   Ss stride 205 (odd -> perfect fp32 bank spread in softmax)
//   Ps stride 264 (528 B = 33*16B, odd multiple), zero-padded past L
constexpr int SSTR = 205;
constexpr int PSTR = 264;

__global__ __launch_bounds__(256)
void attn_mfma(const __hip_bfloat16* __restrict__ qkv, __hip_bfloat16* __restrict__ o,
               int L, int QT) {
    __shared__ __hip_bfloat16 Qs[32 * 72];
    __shared__ __hip_bfloat16 Ks[64 * 72];      // K chunk in pass 1, V^T chunk in pass 2
    __shared__ float Ss[32 * SSTR];
    __shared__ __hip_bfloat16 Ps[32 * PSTR];
    __shared__ float red8[256];
    __shared__ float rowstat[32];
    int tid = threadIdx.x;
    int lane = tid & 63;
    int wave = tid >> 6;
    int idx = blockIdx.x;
    int qt = idx % QT; idx /= QT;
    int h = idx % NHEAD;
    int b = idx / NHEAD;
    int q0 = qt * 32;
    const __hip_bfloat16* base = qkv + (size_t)b * L * 2304 + h * 64;
    int fr = lane & 15, fg = lane >> 4;

    // load Q tile (32 rows x 64 d), zero-padded
    {
        int row = tid >> 3, dg = (tid & 7) * 8;
        short8 s = {0, 0, 0, 0, 0, 0, 0, 0};
        if (q0 + row < L) s = *(const short8*)(base + (size_t)(q0 + row) * 2304 + dg);
        *(short8*)&Qs[row * 72 + dg] = s;
    }
    int nchunk = (L + 63) >> 6;
    short8 aq[2][2];

    // ---- pass 1: S = Q K^T * scale ----
    for (int jc = 0; jc < nchunk; jc++) {
        __syncthreads();
        {
            int key = tid >> 2, dg = (tid & 3) * 16;
            int j = jc * 64 + key;
            short8 s0 = {0, 0, 0, 0, 0, 0, 0, 0}, s1 = s0;
            if (j < L) {
                const __hip_bfloat16* src = base + (size_t)j * 2304 + 768 + dg;
                s0 = *(const short8*)src;
                s1 = *(const short8*)(src + 8);
            }
            *(short8*)&Ks[key * 72 + dg] = s0;
            *(short8*)&Ks[key * 72 + dg + 8] = s1;
        }
        __syncthreads();
        if (jc == 0) {
#pragma unroll
            for (int qi = 0; qi < 2; qi++)
#pragma unroll
                for (int kh = 0; kh < 2; kh++)
                    aq[qi][kh] = *(const short8*)&Qs[(qi * 16 + fr) * 72 + kh * 32 + fg * 8];
        }
        short8 bk[2];
#pragma unroll
        for (int kh = 0; kh < 2; kh++)
            bk[kh] = *(const short8*)&Ks[(wave * 16 + fr) * 72 + kh * 32 + fg * 8];
        int col = jc * 64 + wave * 16 + fr;
#pragma unroll
        for (int qi = 0; qi < 2; qi++) {
            float4v acc = {};
            acc = __builtin_amdgcn_mfma_f32_16x16x32_bf16(aq[qi][0], bk[0], acc, 0, 0, 0);
            acc = __builtin_amdgcn_mfma_f32_16x16x32_bf16(aq[qi][1], bk[1], acc, 0, 0, 0);
            if (col < L) {
#pragma unroll
                for (int r = 0; r < 4; r++)
                    Ss[(qi * 16 + fg * 4 + r) * SSTR + col] = acc[r] * ATT_SCALE;
            }
        }
    }
    __syncthreads();

    // ---- softmax (8 threads per row), P -> bf16, zero-padded to nchunk*64 ----
    {
        int q = tid & 31, c = tid >> 5;
        float mx = -1e30f;
        for (int j = c; j < L; j += 8) mx = fmaxf(mx, Ss[q * SSTR + j]);
        red8[c * 32 + q] = mx;
        __syncthreads();
        if (tid < 32) {
            float m2 = red8[tid];
#pragma unroll
            for (int cc = 1; cc < 8; cc++) m2 = fmaxf(m2, red8[cc * 32 + tid]);
            rowstat[tid] = m2;
        }
        __syncthreads();
        mx = rowstat[q];
        float sm = 0.f;
        int NC64 = nchunk * 64;
        for (int j = c; j < NC64; j += 8) {
            float e = 0.f;
            if (j < L) { e = __expf(Ss[q * SSTR + j] - mx); sm += e; }
            Ps[q * PSTR + j] = __float2bfloat16(e);
        }
        red8[c * 32 + q] = sm;
        __syncthreads();
        if (tid < 32) {
            float s2 = red8[tid];
#pragma unroll
            for (int cc = 1; cc < 8; cc++) s2 += red8[cc * 32 + tid];
            rowstat[tid] = 1.0f / s2;
        }
    }

    // ---- pass 2: O = P V ----
    float4v acco[2] = {};
    for (int jc = 0; jc < nchunk; jc++) {
        __syncthreads();
        {
            int key = tid >> 2, dg = (tid & 3) * 16;
            int j = jc * 64 + key;
            short8 s0 = {0, 0, 0, 0, 0, 0, 0, 0}, s1 = s0;
            if (j < L) {
                const __hip_bfloat16* src = base + (size_t)j * 2304 + 1536 + dg;
                s0 = *(const short8*)src;
                s1 = *(const short8*)(src + 8);
            }
            const __hip_bfloat16* e0 = (const __hip_bfloat16*)&s0;
            const __hip_bfloat16* e1 = (const __hip_bfloat16*)&s1;
#pragma unroll
            for (int i2 = 0; i2 < 8; i2++) {
                Ks[(dg + i2) * 72 + key] = e0[i2];
                Ks[(dg + 8 + i2) * 72 + key] = e1[i2];
            }
        }
        __syncthreads();
        short8 ap[2][2], bv[2];
#pragma unroll
        for (int kh = 0; kh < 2; kh++)
            bv[kh] = *(const short8*)&Ks[(wave * 16 + fr) * 72 + kh * 32 + fg * 8];
#pragma unroll
        for (int qi = 0; qi < 2; qi++)
#pragma unroll
            for (int kh = 0; kh < 2; kh++)
                ap[qi][kh] = *(const short8*)&Ps[(qi * 16 + fr) * PSTR + jc * 64 + kh * 32 + fg * 8];
#pragma unroll
        for (int qi = 0; qi < 2; qi++) {
            acco[qi] = __builtin_amdgcn_mfma_f32_16x16x32_bf16(ap[qi][0], bv[0], acco[qi], 0, 0, 0);
            acco[qi] = __builtin_amdgcn_mfma_f32_16x16x32_bf16(ap[qi][1], bv[1], acco[qi], 0, 0, 0);
        }
    }
#pragma unroll
    for (int qi = 0; qi < 2; qi++) {
#pragma unroll
        for (int r = 0; r < 4; r++) {
            int q = qi * 16 + fg * 4 + r;
            if (q0 + q < L) {
                float inv = rowstat[q];
                o[((size_t)(b * L + q0 + q)) * 768 + h * 64 + wave * 16 + fr] =
                    __float2bfloat16(acco[qi][r] * inv);
            }
        }
    }
}

// ---------------- predictor helpers ----------------
__global__ void globmean_kernel(const float* __restrict__ hp, float* __restrict__ glob, int Lc) {
    int b = blockIdx.x;
    int c = threadIdx.x;
    float s = 0.f;
    for (int l = 0; l < Lc; l++) s += hp[((size_t)(b * Lc + l)) * 768 + 384 + c];
    glob[b * 384 + c] = s / (float)Lc;
}

__global__ void globbcast_kernel(float* __restrict__ hp, const float* __restrict__ glob, int Lc) {
    int row = blockIdx.x;
    int b = row / Lc;
    int c = threadIdx.x;
    hp[(size_t)row * 768 + 384 + c] = glob[b * 384 + c];
}

__global__ __launch_bounds__(256)
void score_kernel(const float* __restrict__ p2, const float* __restrict__ w3,
                  const float* __restrict__ b3, float* __restrict__ score) {
    __shared__ float red[256];
    int row = blockIdx.x;
    int tid = threadIdx.x;
    red[tid] = (tid < 192) ? p2[(size_t)row * 192 + tid] * w3[tid] : 0.f;
    __syncthreads();
    for (int st = 128; st > 0; st >>= 1) {
        if (tid < st) red[tid] += red[tid + st];
        __syncthreads();
    }
    if (tid == 0) {
        float x = red[0] + b3[0];
        score[row] = fminf(x, 0.0f) - log1pf(__expf(-fabsf(x)));
    }
}

// ---------------- top-k (set-equivalent to jax.lax.top_k) ----------------
__global__ void topk_kernel(const float* __restrict__ score, int* __restrict__ kidx,
                            int Lc, int k) {
    __shared__ float s[196];
    __shared__ int keep[196];
    int b = blockIdx.x, tid = threadIdx.x;
    for (int i = tid; i < Lc; i += 256) s[i] = score[b * Lc + i];
    __syncthreads();
    for (int i = tid; i < Lc; i += 256) {
        float si = s[i];
        int rank = 0;
        for (int j = 0; j < Lc; j++) {
            float sj = s[j];
            rank += (sj > si) || (sj == si && j < i);
        }
        keep[i] = (rank < k) ? 1 : 0;
    }
    __syncthreads();
    for (int i = tid; i < Lc; i += 256) {
        if (keep[i]) {
            int pos = 0;
            for (int j = 0; j < i; j++) pos += keep[j];
            kidx[b * MAXK + pos] = i;
        }
    }
}

__global__ void gather_kernel(const float* __restrict__ t, const int* __restrict__ kidx,
                              float* __restrict__ dst, int L, int Lnew) {
    int row = blockIdx.x;
    int b = row / Lnew, m = row % Lnew;
    int srcrow = (m == 0) ? b * L : b * L + 1 + kidx[b * MAXK + m - 1];
    const float* sp = t + (size_t)srcrow * 768;
    float* dp = dst + (size_t)row * 768;
    for (int c = threadIdx.x; c < 768; c += 256) dp[c] = sp[c];
}

// ---------------- host orchestration ----------------
extern "C" void kernel_launch(void* const* d_in, const int* in_sizes, int n_in,
                              void* d_out, int out_size, void* d_ws, size_t ws_size,
                              hipStream_t stream) {
    const float* x        = (const float*)d_in[0];
    const float* patch_w  = (const float*)d_in[1];
    const float* patch_b  = (const float*)d_in[2];
    const float* cls_tok  = (const float*)d_in[3];
    const float* pos_emb  = (const float*)d_in[4];
    const float* ln1_g    = (const float*)d_in[5];
    const float* ln1_b    = (const float*)d_in[6];
    const float* qkv_w    = (const float*)d_in[7];
    const float* qkv_b    = (const float*)d_in[8];
    const float* proj_w   = (const float*)d_in[9];
    const float* proj_b   = (const float*)d_in[10];
    const float* ln2_g    = (const float*)d_in[11];
    const float* ln2_b    = (const float*)d_in[12];
    const float* fc1_w    = (const float*)d_in[13];
    const float* fc1_b    = (const float*)d_in[14];
    const float* fc2_w    = (const float*)d_in[15];
    const float* fc2_b    = (const float*)d_in[16];
    const float* pln_g    = (const float*)d_in[17];
    const float* pln_b    = (const float*)d_in[18];
    const float* pin_w    = (const float*)d_in[19];
    const float* pin_b    = (const float*)d_in[20];
    const float* pw1      = (const float*)d_in[21];
    const float* pb1      = (const float*)d_in[22];
    const float* pw2      = (const float*)d_in[23];
    const float* pb2      = (const float*)d_in[24];
    const float* pw3      = (const float*)d_in[25];
    const float* pb3      = (const float*)d_in[26];
    const float* norm_g   = (const float*)d_in[27];
    const float* norm_b   = (const float*)d_in[28];
    const float* head_w   = (const float*)d_in[29];
    const float* head_b   = (const float*)d_in[30];

    float* ws = (float*)d_ws;
    float* cur   = ws + OFF_T0;
    float* tmp   = ws + OFF_T1;
    float* C32   = ws + OFF_C32;
    __hip_bfloat16* ABF = (__hip_bfloat16*)(ws + OFF_ABF);
    __hip_bfloat16* WL  = (__hip_bfloat16*)(ws + OFF_WL);
    __hip_bfloat16* QBF = (__hip_bfloat16*)C32;  // qkv bf16 out overlays C32 region
    __hip_bfloat16* BBF = (__hip_bfloat16*)C32;  // fc1 bf16 out overlays C32 region
    float* GLOB  = ws + OFF_GLOB;
    float* SCORE = ws + OFF_SCORE;
    int*   KIDX  = (int*)(ws + OFF_KIDX);
    float* CLS   = ws + OFF_CLS;

    // patch embed
    cvt(stream, patch_w, WL, 768 * 768);
    patch_kernel<<<(BATCH * 196 * 768) / 256, 256, 0, stream>>>(x, ABF);
    gemm_bf<float>(stream, ABF, WL, patch_b, nullptr, C32, BATCH * 196, 768, 768, 0);
    assemble_kernel<<<BATCH * 197, 256, 0, stream>>>(C32, cls_tok, pos_emb, cur);

    int L = 197;
    for (int i = 0; i < DEPTH; i++) {
        bool isprune = (i == 3 || i == 6 || i == 9);
        // fused per-layer weight conversion (single launch)
        {
            int nblk = isprune ? 3744 : 3456;
            const float* pin_src = isprune ? pin_w + (size_t)(i / 3 - 1) * 768 * 768 : qkv_w;
            cvt_layer_kernel<<<nblk, 256, 0, stream>>>(
                qkv_w + (size_t)i * 2304 * 768, proj_w + (size_t)i * 768 * 768,
                fc1_w + (size_t)i * 3072 * 768, fc2_w + (size_t)i * 768 * 3072,
                pin_src, WL);
        }
        if (isprune) {
            int s = i / 3 - 1;
            int Lc = L - 1;
            int k = (7 * Lc + 9) / 10;  // ceil(0.7*Lc)
            ln_kernel<__hip_bfloat16><<<BATCH * Lc, 256, 0, stream>>>(
                cur, ABF, pln_g + s * 768, pln_b + s * 768, Lc, L, 1, Lc, 0);
            gemm_bf<float>(stream, ABF, WL + W_PIN, pin_b + s * 768, nullptr, C32,
                           BATCH * Lc, 768, 768, 1);
            globmean_kernel<<<BATCH, 384, 0, stream>>>(C32, GLOB, Lc);
            globbcast_kernel<<<BATCH * Lc, 384, 0, stream>>>(C32, GLOB, Lc);
            gemm(stream, C32, pw1 + (size_t)s * 384 * 768, pb1 + s * 384, nullptr, tmp,
                 BATCH * Lc, 384, 768, 1);
            float* P2 = tmp + 2500000;
            gemm(stream, tmp, pw2 + (size_t)s * 192 * 384, pb2 + s * 192, nullptr, P2,
                 BATCH * Lc, 192, 384, 1);
            score_kernel<<<BATCH * Lc, 256, 0, stream>>>(P2, pw3 + s * 192, pb3 + s, SCORE);
            topk_kernel<<<BATCH, 256, 0, stream>>>(SCORE, KIDX, Lc, k);
            int Lnew = k + 1;
            gather_kernel<<<BATCH * Lnew, 256, 0, stream>>>(cur, KIDX, tmp, L, Lnew);
            float* t_ = cur; cur = tmp; tmp = t_;
            L = Lnew;
        }
        int M = BATCH * L;
        int QT = (L + 31) / 32;
        // attention
        ln_kernel<__hip_bfloat16><<<M, 256, 0, stream>>>(
            cur, ABF, ln1_g + i * 768, ln1_b + i * 768, L, L, 0, L, 0);
        gemm_bf<__hip_bfloat16>(stream, ABF, WL + W_QKV, qkv_b + i * 2304, nullptr, QBF,
                                M, 2304, 768, 0);
        attn_mfma<<<BATCH * NHEAD * QT, 256, 0, stream>>>(QBF, ABF, L, QT);
        gemm_bf<float>(stream, ABF, WL + W_PROJ, proj_b + i * 768, cur, cur, M, 768, 768, 2);
        // MLP
        ln_kernel<__hip_bfloat16><<<M, 256, 0, stream>>>(
            cur, ABF, ln2_g + i * 768, ln2_b + i * 768, L, L, 0, L, 0);
        gemm_bf<__hip_bfloat16>(stream, ABF, WL + W_FC1, fc1_b + i * 3072, nullptr, BBF,
                                M, 3072, 768, 1);
        gemm_bf<float>(stream, BBF, WL + W_FC2, fc2_b + i * 768, cur, cur, M, 768, 3072, 2);
    }
    ln_kernel<float><<<BATCH, 256, 0, stream>>>(cur, CLS, norm_g, norm_b, 1, L, 0, 1, 0);
    gemm(stream, CLS, head_w, head_b, nullptr, (float*)d_out, BATCH, 1000, 768, 0);
}

// Round 3
// 3469.094 us; speedup vs baseline: 1.1889x; 1.0997x over previous
//
#include <hip/hip_runtime.h>
#include <hip/hip_bf16.h>
#include <math.h>

// ---------------- model constants ----------------
constexpr int BATCH = 32;
constexpr int NHEAD = 12;
constexpr int DEPTH = 12;
constexpr int L0TOK = 196;
constexpr int MAXK = 138;
constexpr float ATT_SCALE = 0.125f;

// workspace layout (float-slot offsets)
constexpr size_t SZ_T = (size_t)BATCH * 197 * 768;            // 4,841,472
constexpr size_t OFF_T0 = 0;
constexpr size_t OFF_T1 = SZ_T;
constexpr size_t OFF_C32 = 2 * SZ_T;                          // 14,524,416 floats
constexpr size_t OFF_ABF = OFF_C32 + (size_t)BATCH * 197 * 2304;   // bf16 activations (2,420,736 slots)
constexpr size_t OFF_WL  = OFF_ABF + 2420736;                 // bf16 weights: 7,667,712 bf16 = 3,833,856 float slots
constexpr size_t OFF_GLOB  = OFF_WL + 3833856;
constexpr size_t OFF_SCORE = OFF_GLOB + (size_t)BATCH * 384;
constexpr size_t OFF_KIDX  = OFF_SCORE + (size_t)BATCH * L0TOK;
constexpr size_t OFF_CLS   = OFF_KIDX + (size_t)BATCH * 140;

// per-layer bf16 weight sub-offsets (bf16-element units)
constexpr size_t W_QKV  = 0;               // 2304*768 = 1,769,472
constexpr size_t W_PROJ = 1769472;         // 768*768  =   589,824
constexpr size_t W_FC1  = 2359296;         // 3072*768 = 2,359,296
constexpr size_t W_FC2  = 4718592;         // 768*3072 = 2,359,296
constexpr size_t W_PIN  = 7077888;         // 768*768  =   589,824

typedef __attribute__((ext_vector_type(8))) short short8;
typedef __attribute__((ext_vector_type(4))) float float4v;

__device__ __forceinline__ float gelu_f(float x) {
    return 0.5f * x * (1.0f + erff(x * 0.7071067811865476f));
}
__device__ __forceinline__ float bf2f(short s) {
    return __uint_as_float(((unsigned)(unsigned short)s) << 16);
}

// async 16B global->LDS (DMA, no VGPR round trip)
__device__ __forceinline__ void load_lds16(const void* g, void* l) {
    __builtin_amdgcn_global_load_lds(
        (const __attribute__((address_space(1))) unsigned int*)g,
        (__attribute__((address_space(3))) unsigned int*)l, 16, 0, 0);
}

// ---------------- fp32 -> bf16 weight conversion ----------------
__global__ void cvt_kernel(const float* __restrict__ src, __hip_bfloat16* __restrict__ dst, int n) {
    int i = (blockIdx.x * 256 + threadIdx.x) * 4;
    if (i >= n) return;
    float4 v = *(const float4*)(src + i);
    dst[i + 0] = __float2bfloat16(v.x);
    dst[i + 1] = __float2bfloat16(v.y);
    dst[i + 2] = __float2bfloat16(v.z);
    dst[i + 3] = __float2bfloat16(v.w);
}
static inline void cvt(hipStream_t st, const float* s, __hip_bfloat16* d, size_t n) {
    cvt_kernel<<<(n / 4 + 255) / 256, 256, 0, st>>>(s, d, (int)n);
}

// fused per-layer weight convert: qkv|proj|fc1|fc2[|pin] in one launch.
__global__ void cvt_layer_kernel(const float* __restrict__ wqkv, const float* __restrict__ wproj,
                                 const float* __restrict__ wfc1, const float* __restrict__ wfc2,
                                 const float* __restrict__ wpin, __hip_bfloat16* __restrict__ dst) {
    size_t i = ((size_t)blockIdx.x * 256 + threadIdx.x) * 8;
    const float* src;
    size_t off;
    if (i < W_PROJ)      { src = wqkv;  off = i; }
    else if (i < W_FC1)  { src = wproj; off = i - W_PROJ; }
    else if (i < W_FC2)  { src = wfc1;  off = i - W_FC1; }
    else if (i < W_PIN)  { src = wfc2;  off = i - W_FC2; }
    else                 { src = wpin;  off = i - W_PIN; }
    float4 a = *(const float4*)(src + off);
    float4 b = *(const float4*)(src + off + 4);
    union { short8 v; __hip_bfloat16 h[8]; } u;
    u.h[0] = __float2bfloat16(a.x); u.h[1] = __float2bfloat16(a.y);
    u.h[2] = __float2bfloat16(a.z); u.h[3] = __float2bfloat16(a.w);
    u.h[4] = __float2bfloat16(b.x); u.h[5] = __float2bfloat16(b.y);
    u.h[6] = __float2bfloat16(b.z); u.h[7] = __float2bfloat16(b.w);
    *(short8*)(dst + i) = u.v;
}

// ---------------- patch rearrange (bf16 out) ----------------
__global__ void patch_kernel(const float* __restrict__ x, __hip_bfloat16* __restrict__ p) {
    int idx = blockIdx.x * 256 + threadIdx.x;
    int c = idx % 768;
    int rest = idx / 768;
    int l = rest % 196;
    int b = rest / 196;
    int ch = c >> 8;
    int py = (c & 255) >> 4;
    int px = c & 15;
    int gy = l / 14, gx = l % 14;
    p[idx] = __float2bfloat16(
        x[(((size_t)b * 3 + ch) * 224 + gy * 16 + py) * 224 + gx * 16 + px]);
}

// ---------------- assemble t = [cls; patches] + pos (fp32) ----------------
__global__ void assemble_kernel(const float* __restrict__ pe, const float* __restrict__ cls,
                                const float* __restrict__ pos, float* __restrict__ t) {
    int row = blockIdx.x;
    int b = row / 197, l = row % 197;
    for (int c = threadIdx.x; c < 768; c += 256) {
        float v = (l == 0) ? cls[c] : pe[((size_t)(b * 196 + l - 1)) * 768 + c];
        t[(size_t)row * 768 + c] = v + pos[l * 768 + c];
    }
}

// ---------------- layernorm, templated output type ----------------
template <typename OT>
__global__ __launch_bounds__(256)
void ln_kernel(const float* __restrict__ src, OT* __restrict__ dst,
               const float* __restrict__ g, const float* __restrict__ bb,
               int R, int SB, int SO, int DB, int DO_) {
    __shared__ float red[256];
    int row = blockIdx.x;
    int b = row / R, r = row % R;
    const float* sp = src + ((size_t)b * SB + SO + r) * 768;
    OT* dp = dst + ((size_t)b * DB + DO_ + r) * 768;
    int tid = threadIdx.x;
    float x0 = sp[tid], x1 = sp[tid + 256], x2 = sp[tid + 512];
    red[tid] = x0 + x1 + x2;
    __syncthreads();
    for (int st = 128; st > 0; st >>= 1) {
        if (tid < st) red[tid] += red[tid + st];
        __syncthreads();
    }
    float mean = red[0] * (1.0f / 768.0f);
    __syncthreads();
    float d0 = x0 - mean, d1 = x1 - mean, d2 = x2 - mean;
    red[tid] = d0 * d0 + d1 * d1 + d2 * d2;
    __syncthreads();
    for (int st = 128; st > 0; st >>= 1) {
        if (tid < st) red[tid] += red[tid + st];
        __syncthreads();
    }
    float inv = rsqrtf(red[0] * (1.0f / 768.0f) + 1e-6f);
    dp[tid]       = (OT)(d0 * inv * g[tid]       + bb[tid]);
    dp[tid + 256] = (OT)(d1 * inv * g[tid + 256] + bb[tid + 256]);
    dp[tid + 512] = (OT)(d2 * inv * g[tid + 512] + bb[tid + 512]);
}

// ---------------- MFMA GEMM: C = A(MxK,bf16) @ W(NxK,bf16)^T + bias ----------------
template <int EPI, typename CT>
__global__ __launch_bounds__(256)
void gemm_mfma(const __hip_bfloat16* __restrict__ A, const __hip_bfloat16* __restrict__ W,
               const float* __restrict__ bias, const float* __restrict__ res,
               CT* __restrict__ C, int M, int N, int K) {
    __shared__ __hip_bfloat16 As[128 * 32];
    __shared__ __hip_bfloat16 Bs[128 * 32];
    int tid = threadIdx.x;
    int lane = tid & 63;
    int wave = tid >> 6;
    int m0 = blockIdx.y * 128, n0 = blockIdx.x * 128;
    int wm = (wave >> 1) * 64, wn = (wave & 1) * 64;

    int c0 = tid, c1 = tid + 256;
    int ra0 = c0 >> 2, ka0 = (c0 & 3) << 3;
    int ra1 = c1 >> 2, ka1 = (c1 & 3) << 3;
    const __hip_bfloat16* pa0 = A + (size_t)(m0 + ra0) * K + ka0;
    const __hip_bfloat16* pa1 = A + (size_t)(m0 + ra1) * K + ka1;
    const __hip_bfloat16* pb0 = W + (size_t)(n0 + ra0) * K + ka0;
    const __hip_bfloat16* pb1 = W + (size_t)(n0 + ra1) * K + ka1;
    __hip_bfloat16* la0 = &As[c0 * 8];
    __hip_bfloat16* la1 = &As[c1 * 8];
    __hip_bfloat16* lb0 = &Bs[c0 * 8];
    __hip_bfloat16* lb1 = &Bs[c1 * 8];
    bool va0 = (m0 + ra0) < M, va1 = (m0 + ra1) < M;

    const short* Asp = (const short*)As + (wm + (lane & 15)) * 32 + (lane >> 4) * 8;
    const short* Bsp = (const short*)Bs + (wn + (lane & 15)) * 32 + (lane >> 4) * 8;

    float4v acc[4][4] = {};
    for (int kb = 0; kb < K; kb += 32) {
        if (va0) load_lds16(pa0, la0);
        if (va1) load_lds16(pa1, la1);
        load_lds16(pb0, lb0);
        load_lds16(pb1, lb1);
        pa0 += 32; pa1 += 32; pb0 += 32; pb1 += 32;
        __syncthreads();
        short8 a[4], b[4];
#pragma unroll
        for (int i = 0; i < 4; i++) a[i] = *(const short8*)(Asp + i * 512);
#pragma unroll
        for (int j = 0; j < 4; j++) b[j] = *(const short8*)(Bsp + j * 512);
#pragma unroll
        for (int i = 0; i < 4; i++)
#pragma unroll
            for (int j = 0; j < 4; j++)
                acc[i][j] = __builtin_amdgcn_mfma_f32_16x16x32_bf16(a[i], b[j], acc[i][j], 0, 0, 0);
        __syncthreads();
    }
    int rbase = m0 + wm + (lane >> 4) * 4;
    int cbase = n0 + wn + (lane & 15);
    float bi[4];
#pragma unroll
    for (int j = 0; j < 4; j++) bi[j] = bias[cbase + j * 16];
#pragma unroll
    for (int i = 0; i < 4; i++) {
#pragma unroll
        for (int r = 0; r < 4; r++) {
            int row = rbase + i * 16 + r;
            if (row >= M) continue;
#pragma unroll
            for (int j = 0; j < 4; j++) {
                int col = cbase + j * 16;
                float v = acc[i][j][r] + bi[j];
                if (EPI == 1) v = gelu_f(v);
                if (EPI == 2) v += res[(size_t)row * N + col];
                C[(size_t)row * N + col] = (CT)v;
            }
        }
    }
}

// 128x64 tile variant — for small grids / narrow N (late layers, predictor).
template <int EPI, typename CT>
__global__ __launch_bounds__(256)
void gemm_mfma_n64(const __hip_bfloat16* __restrict__ A, const __hip_bfloat16* __restrict__ W,
                   const float* __restrict__ bias, const float* __restrict__ res,
                   CT* __restrict__ C, int M, int N, int K) {
    __shared__ __hip_bfloat16 As[128 * 32];
    __shared__ __hip_bfloat16 Bs[64 * 32];
    int tid = threadIdx.x;
    int lane = tid & 63;
    int wave = tid >> 6;
    int m0 = blockIdx.y * 128, n0 = blockIdx.x * 64;
    int wm = (wave >> 1) * 64, wn = (wave & 1) * 32;

    int c0 = tid, c1 = tid + 256;
    int ra0 = c0 >> 2, ka0 = (c0 & 3) << 3;
    int ra1 = c1 >> 2, ka1 = (c1 & 3) << 3;
    int rb  = tid >> 2, kb_ = (tid & 3) << 3;
    const __hip_bfloat16* pa0 = A + (size_t)(m0 + ra0) * K + ka0;
    const __hip_bfloat16* pa1 = A + (size_t)(m0 + ra1) * K + ka1;
    const __hip_bfloat16* pb  = W + (size_t)(n0 + rb) * K + kb_;
    __hip_bfloat16* la0 = &As[c0 * 8];
    __hip_bfloat16* la1 = &As[c1 * 8];
    __hip_bfloat16* lb  = &Bs[tid * 8];
    bool va0 = (m0 + ra0) < M, va1 = (m0 + ra1) < M;

    const short* Asp = (const short*)As + (wm + (lane & 15)) * 32 + (lane >> 4) * 8;
    const short* Bsp = (const short*)Bs + (wn + (lane & 15)) * 32 + (lane >> 4) * 8;

    float4v acc[4][2] = {};
    for (int kb = 0; kb < K; kb += 32) {
        if (va0) load_lds16(pa0, la0);
        if (va1) load_lds16(pa1, la1);
        load_lds16(pb, lb);
        pa0 += 32; pa1 += 32; pb += 32;
        __syncthreads();
        short8 a[4], b[2];
#pragma unroll
        for (int i = 0; i < 4; i++) a[i] = *(const short8*)(Asp + i * 512);
#pragma unroll
        for (int j = 0; j < 2; j++) b[j] = *(const short8*)(Bsp + j * 512);
#pragma unroll
        for (int i = 0; i < 4; i++)
#pragma unroll
            for (int j = 0; j < 2; j++)
                acc[i][j] = __builtin_amdgcn_mfma_f32_16x16x32_bf16(a[i], b[j], acc[i][j], 0, 0, 0);
        __syncthreads();
    }
    int rbase = m0 + wm + (lane >> 4) * 4;
    int cbase = n0 + wn + (lane & 15);
    float bi[2];
#pragma unroll
    for (int j = 0; j < 2; j++) bi[j] = bias[cbase + j * 16];
#pragma unroll
    for (int i = 0; i < 4; i++) {
#pragma unroll
        for (int r = 0; r < 4; r++) {
            int row = rbase + i * 16 + r;
            if (row >= M) continue;
#pragma unroll
            for (int j = 0; j < 2; j++) {
                int col = cbase + j * 16;
                float v = acc[i][j][r] + bi[j];
                if (EPI == 1) v = gelu_f(v);
                if (EPI == 2) v += res[(size_t)row * N + col];
                C[(size_t)row * N + col] = (CT)v;
            }
        }
    }
}

template <typename CT>
static inline void gemm_bf(hipStream_t st, const __hip_bfloat16* A, const __hip_bfloat16* W,
                           const float* bias, const float* res, CT* C,
                           int M, int N, int K, int epi) {
    long blocks128 = (long)(N / 128) * ((M + 127) / 128);
    if (N % 128 == 0 && blocks128 >= 160) {
        dim3 g(N / 128, (M + 127) / 128), b(256);
        if (epi == 0)      gemm_mfma<0, CT><<<g, b, 0, st>>>(A, W, bias, res, C, M, N, K);
        else if (epi == 1) gemm_mfma<1, CT><<<g, b, 0, st>>>(A, W, bias, res, C, M, N, K);
        else               gemm_mfma<2, CT><<<g, b, 0, st>>>(A, W, bias, res, C, M, N, K);
    } else {
        dim3 g(N / 64, (M + 127) / 128), b(256);
        if (epi == 0)      gemm_mfma_n64<0, CT><<<g, b, 0, st>>>(A, W, bias, res, C, M, N, K);
        else if (epi == 1) gemm_mfma_n64<1, CT><<<g, b, 0, st>>>(A, W, bias, res, C, M, N, K);
        else               gemm_mfma_n64<2, CT><<<g, b, 0, st>>>(A, W, bias, res, C, M, N, K);
    }
}

// ---------------- fp32 GEMM (head matmul only) ----------------
template <int EPI>
__global__ __launch_bounds__(256)
void gemm_kernel(const float* __restrict__ A, const float* __restrict__ W,
                 const float* __restrict__ bias, const float* __restrict__ res,
                 float* __restrict__ C, int M, int N, int K) {
    __shared__ float As[16][128];
    __shared__ float Ws[16][64];
    int tid = threadIdx.x;
    int tx = tid & 15, ty = tid >> 4;
    int m0 = blockIdx.y * 128, n0 = blockIdx.x * 64;
    int arow = tid >> 1;
    int akh = (tid & 1) * 8;
    int brow = tid & 63;
    int bkq = (tid >> 6) * 4;
    const float* Arow = A + (size_t)(m0 + arow) * K;
    const float* Wrow = W + (size_t)(n0 + brow) * K;
    bool aval = (m0 + arow) < M;
    bool bval = (n0 + brow) < N;
    float acc[8][4] = {};
    for (int kb = 0; kb < K; kb += 16) {
        float4 av0 = make_float4(0.f, 0.f, 0.f, 0.f), av1 = av0, bv0 = av0;
        if (aval) {
            av0 = *(const float4*)(Arow + kb + akh);
            av1 = *(const float4*)(Arow + kb + akh + 4);
        }
        if (bval) bv0 = *(const float4*)(Wrow + kb + bkq);
        __syncthreads();
        As[akh + 0][arow] = av0.x; As[akh + 1][arow] = av0.y;
        As[akh + 2][arow] = av0.z; As[akh + 3][arow] = av0.w;
        As[akh + 4][arow] = av1.x; As[akh + 5][arow] = av1.y;
        As[akh + 6][arow] = av1.z; As[akh + 7][arow] = av1.w;
        Ws[bkq + 0][brow] = bv0.x; Ws[bkq + 1][brow] = bv0.y;
        Ws[bkq + 2][brow] = bv0.z; Ws[bkq + 3][brow] = bv0.w;
        __syncthreads();
#pragma unroll
        for (int kk = 0; kk < 16; kk++) {
            float4 a0 = *(const float4*)&As[kk][ty * 8];
            float4 a1 = *(const float4*)&As[kk][ty * 8 + 4];
            float4 b0 = *(const float4*)&Ws[kk][tx * 4];
            float a[8] = {a0.x, a0.y, a0.z, a0.w, a1.x, a1.y, a1.z, a1.w};
            float bb4[4] = {b0.x, b0.y, b0.z, b0.w};
#pragma unroll
            for (int i = 0; i < 8; i++)
#pragma unroll
                for (int j = 0; j < 4; j++) acc[i][j] += a[i] * bb4[j];
        }
    }
#pragma unroll
    for (int i = 0; i < 8; i++) {
        int m = m0 + ty * 8 + i;
        if (m >= M) break;
        int n = n0 + tx * 4;
        if (n >= N) continue;
        float4 v = make_float4(acc[i][0] + bias[n], acc[i][1] + bias[n + 1],
                               acc[i][2] + bias[n + 2], acc[i][3] + bias[n + 3]);
        if (EPI == 1) {
            v.x = gelu_f(v.x); v.y = gelu_f(v.y); v.z = gelu_f(v.z); v.w = gelu_f(v.w);
        }
        if (EPI == 2) {
            const float4 r = *(const float4*)(res + (size_t)m * N + n);
            v.x += r.x; v.y += r.y; v.z += r.z; v.w += r.w;
        }
        *(float4*)(C + (size_t)m * N + n) = v;
    }
}

static inline void gemm(hipStream_t st, const float* A, const float* W, const float* bias,
                        const float* res, float* C, int M, int N, int K, int epi) {
    dim3 g((N + 63) / 64, (M + 127) / 128), b(256);
    if (epi == 0)      gemm_kernel<0><<<g, b, 0, st>>>(A, W, bias, res, C, M, N, K);
    else if (epi == 1) gemm_kernel<1><<<g, b, 0, st>>>(A, W, bias, res, C, M, N, K);
    else               gemm_kernel<2><<<g, b, 0, st>>>(A, W, bias, res, C, M, N, K);
}

// ---------------- MFMA attention: block per (b,h,32-query tile), bf16 in/out ----------
constexpr int SSTR = 205;
constexpr int PSTR = 264;

__global__ __launch_bounds__(256)
void attn_mfma(const __hip_bfloat16* __restrict__ qkv, __hip_bfloat16* __restrict__ o,
               int L, int QT) {
    __shared__ __hip_bfloat16 Qs[32 * 72];
    __shared__ __hip_bfloat16 Ks[64 * 72];      // K chunk in pass 1, V^T chunk in pass 2
    __shared__ float Ss[32 * SSTR];
    __shared__ __hip_bfloat16 Ps[32 * PSTR];
    __shared__ float red8[256];
    __shared__ float rowstat[32];
    int tid = threadIdx.x;
    int lane = tid & 63;
    int wave = tid >> 6;
    int idx = blockIdx.x;
    int qt = idx % QT; idx /= QT;
    int h = idx % NHEAD;
    int b = idx / NHEAD;
    int q0 = qt * 32;
    const __hip_bfloat16* base = qkv + (size_t)b * L * 2304 + h * 64;
    int fr = lane & 15, fg = lane >> 4;

    {
        int row = tid >> 3, dg = (tid & 7) * 8;
        short8 s = {0, 0, 0, 0, 0, 0, 0, 0};
        if (q0 + row < L) s = *(const short8*)(base + (size_t)(q0 + row) * 2304 + dg);
        *(short8*)&Qs[row * 72 + dg] = s;
    }
    int nchunk = (L + 63) >> 6;
    short8 aq[2][2];

    // ---- pass 1: S = Q K^T * scale ----
    for (int jc = 0; jc < nchunk; jc++) {
        __syncthreads();
        {
            int key = tid >> 2, dg = (tid & 3) * 16;
            int j = jc * 64 + key;
            short8 s0 = {0, 0, 0, 0, 0, 0, 0, 0}, s1 = s0;
            if (j < L) {
                const __hip_bfloat16* src = base + (size_t)j * 2304 + 768 + dg;
                s0 = *(const short8*)src;
                s1 = *(const short8*)(src + 8);
            }
            *(short8*)&Ks[key * 72 + dg] = s0;
            *(short8*)&Ks[key * 72 + dg + 8] = s1;
        }
        __syncthreads();
        if (jc == 0) {
#pragma unroll
            for (int qi = 0; qi < 2; qi++)
#pragma unroll
                for (int kh = 0; kh < 2; kh++)
                    aq[qi][kh] = *(const short8*)&Qs[(qi * 16 + fr) * 72 + kh * 32 + fg * 8];
        }
        short8 bk[2];
#pragma unroll
        for (int kh = 0; kh < 2; kh++)
            bk[kh] = *(const short8*)&Ks[(wave * 16 + fr) * 72 + kh * 32 + fg * 8];
        int col = jc * 64 + wave * 16 + fr;
#pragma unroll
        for (int qi = 0; qi < 2; qi++) {
            float4v acc = {};
            acc = __builtin_amdgcn_mfma_f32_16x16x32_bf16(aq[qi][0], bk[0], acc, 0, 0, 0);
            acc = __builtin_amdgcn_mfma_f32_16x16x32_bf16(aq[qi][1], bk[1], acc, 0, 0, 0);
            if (col < L) {
#pragma unroll
                for (int r = 0; r < 4; r++)
                    Ss[(qi * 16 + fg * 4 + r) * SSTR + col] = acc[r] * ATT_SCALE;
            }
        }
    }
    __syncthreads();

    // ---- softmax (8 threads per row), P -> bf16, zero-padded to nchunk*64 ----
    {
        int q = tid & 31, c = tid >> 5;
        float mx = -1e30f;
        for (int j = c; j < L; j += 8) mx = fmaxf(mx, Ss[q * SSTR + j]);
        red8[c * 32 + q] = mx;
        __syncthreads();
        if (tid < 32) {
            float m2 = red8[tid];
#pragma unroll
            for (int cc = 1; cc < 8; cc++) m2 = fmaxf(m2, red8[cc * 32 + tid]);
            rowstat[tid] = m2;
        }
        __syncthreads();
        mx = rowstat[q];
        float sm = 0.f;
        int NC64 = nchunk * 64;
        for (int j = c; j < NC64; j += 8) {
            float e = 0.f;
            if (j < L) { e = __expf(Ss[q * SSTR + j] - mx); sm += e; }
            Ps[q * PSTR + j] = __float2bfloat16(e);
        }
        red8[c * 32 + q] = sm;
        __syncthreads();
        if (tid < 32) {
            float s2 = red8[tid];
#pragma unroll
            for (int cc = 1; cc < 8; cc++) s2 += red8[cc * 32 + tid];
            rowstat[tid] = 1.0f / s2;
        }
    }

    // ---- pass 2: O = P V ----
    float4v acco[2] = {};
    for (int jc = 0; jc < nchunk; jc++) {
        __syncthreads();
        {
            int key = tid >> 2, dg = (tid & 3) * 16;
            int j = jc * 64 + key;
            short8 s0 = {0, 0, 0, 0, 0, 0, 0, 0}, s1 = s0;
            if (j < L) {
                const __hip_bfloat16* src = base + (size_t)j * 2304 + 1536 + dg;
                s0 = *(const short8*)src;
                s1 = *(const short8*)(src + 8);
            }
            const __hip_bfloat16* e0 = (const __hip_bfloat16*)&s0;
            const __hip_bfloat16* e1 = (const __hip_bfloat16*)&s1;
#pragma unroll
            for (int i2 = 0; i2 < 8; i2++) {
                Ks[(dg + i2) * 72 + key] = e0[i2];
                Ks[(dg + 8 + i2) * 72 + key] = e1[i2];
            }
        }
        __syncthreads();
        short8 ap[2][2], bv[2];
#pragma unroll
        for (int kh = 0; kh < 2; kh++)
            bv[kh] = *(const short8*)&Ks[(wave * 16 + fr) * 72 + kh * 32 + fg * 8];
#pragma unroll
        for (int qi = 0; qi < 2; qi++)
#pragma unroll
            for (int kh = 0; kh < 2; kh++)
                ap[qi][kh] = *(const short8*)&Ps[(qi * 16 + fr) * PSTR + jc * 64 + kh * 32 + fg * 8];
#pragma unroll
        for (int qi = 0; qi < 2; qi++) {
            acco[qi] = __builtin_amdgcn_mfma_f32_16x16x32_bf16(ap[qi][0], bv[0], acco[qi], 0, 0, 0);
            acco[qi] = __builtin_amdgcn_mfma_f32_16x16x32_bf16(ap[qi][1], bv[1], acco[qi], 0, 0, 0);
        }
    }
#pragma unroll
    for (int qi = 0; qi < 2; qi++) {
#pragma unroll
        for (int r = 0; r < 4; r++) {
            int q = qi * 16 + fg * 4 + r;
            if (q0 + q < L) {
                float inv = rowstat[q];
                o[((size_t)(b * L + q0 + q)) * 768 + h * 64 + wave * 16 + fr] =
                    __float2bfloat16(acco[qi][r] * inv);
            }
        }
    }
}

// ---------------- predictor helpers (bf16 h) ----------------
// partial sums over an 8-way row split; gp[(b*8+c8)*384 + c]
__global__ void globpart_kernel(const __hip_bfloat16* __restrict__ hp, float* __restrict__ gp,
                                int Lc) {
    int blk = blockIdx.x;
    int b = blk >> 3, c8 = blk & 7;
    int c = threadIdx.x;
    int chunk = (Lc + 7) / 8;
    int r0 = c8 * chunk, r1 = min(Lc, r0 + chunk);
    float s = 0.f;
    for (int l = r0; l < r1; l++)
        s += __bfloat162float(hp[((size_t)(b * Lc + l)) * 768 + 384 + c]);
    gp[(size_t)blk * 384 + c] = s;
}

__global__ void globred_kernel(const float* __restrict__ gp, float* __restrict__ glob, int Lc) {
    int b = blockIdx.x;
    int c = threadIdx.x;
    float s = 0.f;
#pragma unroll
    for (int j = 0; j < 8; j++) s += gp[(size_t)(b * 8 + j) * 384 + c];
    glob[b * 384 + c] = s / (float)Lc;
}

__global__ void globbcast_bf(__hip_bfloat16* __restrict__ hp, const float* __restrict__ glob,
                             int Lc) {
    int row = blockIdx.x;
    int b = row / Lc;
    int c = threadIdx.x;
    hp[(size_t)row * 768 + 384 + c] = __float2bfloat16(glob[b * 384 + c]);
}

__global__ __launch_bounds__(256)
void score_kernel(const float* __restrict__ p2, const float* __restrict__ w3,
                  const float* __restrict__ b3, float* __restrict__ score) {
    __shared__ float red[256];
    int row = blockIdx.x;
    int tid = threadIdx.x;
    red[tid] = (tid < 192) ? p2[(size_t)row * 192 + tid] * w3[tid] : 0.f;
    __syncthreads();
    for (int st = 128; st > 0; st >>= 1) {
        if (tid < st) red[tid] += red[tid + st];
        __syncthreads();
    }
    if (tid == 0) {
        float x = red[0] + b3[0];
        score[row] = fminf(x, 0.0f) - log1pf(__expf(-fabsf(x)));
    }
}

// ---------------- top-k (set-equivalent to jax.lax.top_k) ----------------
__global__ void topk_kernel(const float* __restrict__ score, int* __restrict__ kidx,
                            int Lc, int k) {
    __shared__ float s[196];
    __shared__ int keep[196];
    int b = blockIdx.x, tid = threadIdx.x;
    for (int i = tid; i < Lc; i += 256) s[i] = score[b * Lc + i];
    __syncthreads();
    for (int i = tid; i < Lc; i += 256) {
        float si = s[i];
        int rank = 0;
        for (int j = 0; j < Lc; j++) {
            float sj = s[j];
            rank += (sj > si) || (sj == si && j < i);
        }
        keep[i] = (rank < k) ? 1 : 0;
    }
    __syncthreads();
    for (int i = tid; i < Lc; i += 256) {
        if (keep[i]) {
            int pos = 0;
            for (int j = 0; j < i; j++) pos += keep[j];
            kidx[b * MAXK + pos] = i;
        }
    }
}

__global__ void gather_kernel(const float* __restrict__ t, const int* __restrict__ kidx,
                              float* __restrict__ dst, int L, int Lnew) {
    int row = blockIdx.x;
    int b = row / Lnew, m = row % Lnew;
    int srcrow = (m == 0) ? b * L : b * L + 1 + kidx[b * MAXK + m - 1];
    const float* sp = t + (size_t)srcrow * 768;
    float* dp = dst + (size_t)row * 768;
    for (int c = threadIdx.x; c < 768; c += 256) dp[c] = sp[c];
}

// ---------------- host orchestration ----------------
extern "C" void kernel_launch(void* const* d_in, const int* in_sizes, int n_in,
                              void* d_out, int out_size, void* d_ws, size_t ws_size,
                              hipStream_t stream) {
    const float* x        = (const float*)d_in[0];
    const float* patch_w  = (const float*)d_in[1];
    const float* patch_b  = (const float*)d_in[2];
    const float* cls_tok  = (const float*)d_in[3];
    const float* pos_emb  = (const float*)d_in[4];
    const float* ln1_g    = (const float*)d_in[5];
    const float* ln1_b    = (const float*)d_in[6];
    const float* qkv_w    = (const float*)d_in[7];
    const float* qkv_b    = (const float*)d_in[8];
    const float* proj_w   = (const float*)d_in[9];
    const float* proj_b   = (const float*)d_in[10];
    const float* ln2_g    = (const float*)d_in[11];
    const float* ln2_b    = (const float*)d_in[12];
    const float* fc1_w    = (const float*)d_in[13];
    const float* fc1_b    = (const float*)d_in[14];
    const float* fc2_w    = (const float*)d_in[15];
    const float* fc2_b    = (const float*)d_in[16];
    const float* pln_g    = (const float*)d_in[17];
    const float* pln_b    = (const float*)d_in[18];
    const float* pin_w    = (const float*)d_in[19];
    const float* pin_b    = (const float*)d_in[20];
    const float* pw1      = (const float*)d_in[21];
    const float* pb1      = (const float*)d_in[22];
    const float* pw2      = (const float*)d_in[23];
    const float* pb2      = (const float*)d_in[24];
    const float* pw3      = (const float*)d_in[25];
    const float* pb3      = (const float*)d_in[26];
    const float* norm_g   = (const float*)d_in[27];
    const float* norm_b   = (const float*)d_in[28];
    const float* head_w   = (const float*)d_in[29];
    const float* head_b   = (const float*)d_in[30];

    float* ws = (float*)d_ws;
    float* cur   = ws + OFF_T0;
    float* tmp   = ws + OFF_T1;
    float* C32   = ws + OFF_C32;
    __hip_bfloat16* ABF = (__hip_bfloat16*)(ws + OFF_ABF);
    __hip_bfloat16* WL  = (__hip_bfloat16*)(ws + OFF_WL);
    __hip_bfloat16* QBF = (__hip_bfloat16*)C32;  // qkv bf16 out overlays C32 region
    __hip_bfloat16* BBF = (__hip_bfloat16*)C32;  // fc1 bf16 out overlays C32 region
    float* GLOB  = ws + OFF_GLOB;
    float* SCORE = ws + OFF_SCORE;
    int*   KIDX  = (int*)(ws + OFF_KIDX);
    float* CLS   = ws + OFF_CLS;

    // patch embed
    cvt(stream, patch_w, WL, 768 * 768);
    patch_kernel<<<(BATCH * 196 * 768) / 256, 256, 0, stream>>>(x, ABF);
    gemm_bf<float>(stream, ABF, WL, patch_b, nullptr, C32, BATCH * 196, 768, 768, 0);
    assemble_kernel<<<BATCH * 197, 256, 0, stream>>>(C32, cls_tok, pos_emb, cur);

    int L = 197;
    for (int i = 0; i < DEPTH; i++) {
        bool isprune = (i == 3 || i == 6 || i == 9);
        // fused per-layer weight conversion (single launch)
        {
            int nblk = isprune ? 3744 : 3456;
            const float* pin_src = isprune ? pin_w + (size_t)(i / 3 - 1) * 768 * 768 : qkv_w;
            cvt_layer_kernel<<<nblk, 256, 0, stream>>>(
                qkv_w + (size_t)i * 2304 * 768, proj_w + (size_t)i * 768 * 768,
                fc1_w + (size_t)i * 3072 * 768, fc2_w + (size_t)i * 768 * 3072,
                pin_src, WL);
        }
        if (isprune) {
            int s = i / 3 - 1;
            int Lc = L - 1;
            int k = (7 * Lc + 9) / 10;  // ceil(0.7*Lc)
            int Mp = BATCH * Lc;
            // predictor scratch lives in the (currently dead) tmp region
            __hip_bfloat16* HBF   = (__hip_bfloat16*)C32;          // pin out, M x 768 bf16
            __hip_bfloat16* PW1BF = (__hip_bfloat16*)tmp;          // 384*768 bf16
            __hip_bfloat16* PW2BF = (__hip_bfloat16*)(tmp + 150000);
            __hip_bfloat16* P1BF  = (__hip_bfloat16*)(tmp + 200000);  // M x 384 bf16
            float* P2 = tmp + 1500000;                             // M x 192 fp32
            float* GP = tmp + 3000000;                             // 32*8*384 fp32

            ln_kernel<__hip_bfloat16><<<Mp, 256, 0, stream>>>(
                cur, ABF, pln_g + s * 768, pln_b + s * 768, Lc, L, 1, Lc, 0);
            cvt(stream, pw1 + (size_t)s * 384 * 768, PW1BF, 384 * 768);
            cvt(stream, pw2 + (size_t)s * 192 * 384, PW2BF, 192 * 384);
            gemm_bf<__hip_bfloat16>(stream, ABF, WL + W_PIN, pin_b + s * 768, nullptr, HBF,
                                    Mp, 768, 768, 1);
            globpart_kernel<<<BATCH * 8, 384, 0, stream>>>(HBF, GP, Lc);
            globred_kernel<<<BATCH, 384, 0, stream>>>(GP, GLOB, Lc);
            globbcast_bf<<<Mp, 384, 0, stream>>>(HBF, GLOB, Lc);
            gemm_bf<__hip_bfloat16>(stream, HBF, PW1BF, pb1 + s * 384, nullptr, P1BF,
                                    Mp, 384, 768, 1);
            gemm_bf<float>(stream, P1BF, PW2BF, pb2 + s * 192, nullptr, P2,
                           Mp, 192, 384, 1);
            score_kernel<<<Mp, 256, 0, stream>>>(P2, pw3 + s * 192, pb3 + s, SCORE);
            topk_kernel<<<BATCH, 256, 0, stream>>>(SCORE, KIDX, Lc, k);
            int Lnew = k + 1;
            gather_kernel<<<BATCH * Lnew, 256, 0, stream>>>(cur, KIDX, tmp, L, Lnew);
            float* t_ = cur; cur = tmp; tmp = t_;
            L = Lnew;
        }
        int M = BATCH * L;
        int QT = (L + 31) / 32;
        // attention
        ln_kernel<__hip_bfloat16><<<M, 256, 0, stream>>>(
            cur, ABF, ln1_g + i * 768, ln1_b + i * 768, L, L, 0, L, 0);
        gemm_bf<__hip_bfloat16>(stream, ABF, WL + W_QKV, qkv_b + i * 2304, nullptr, QBF,
                                M, 2304, 768, 0);
        attn_mfma<<<BATCH * NHEAD * QT, 256, 0, stream>>>(QBF, ABF, L, QT);
        gemm_bf<float>(stream, ABF, WL + W_PROJ, proj_b + i * 768, cur, cur, M, 768, 768, 2);
        // MLP
        ln_kernel<__hip_bfloat16><<<M, 256, 0, stream>>>(
            cur, ABF, ln2_g + i * 768, ln2_b + i * 768, L, L, 0, L, 0);
        gemm_bf<__hip_bfloat16>(stream, ABF, WL + W_FC1, fc1_b + i * 3072, nullptr, BBF,
                                M, 3072, 768, 1);
        gemm_bf<float>(stream, BBF, WL + W_FC2, fc2_b + i * 768, cur, cur, M, 768, 3072, 2);
    }
    ln_kernel<float><<<BATCH, 256, 0, stream>>>(cur, CLS, norm_g, norm_b, 1, L, 0, 1, 0);
    gemm(stream, CLS, head_w, head_b, nullptr, (float*)d_out, BATCH, 1000, 768, 0);
}

// Round 4
// 3265.746 us; speedup vs baseline: 1.2629x; 1.0623x over previous
//
#include <hip/hip_runtime.h>
#include <hip/hip_bf16.h>
#include <math.h>

// ---------------- model constants ----------------
constexpr int BATCH = 32;
constexpr int NHEAD = 12;
constexpr int DEPTH = 12;
constexpr int L0TOK = 196;
constexpr int MAXK = 138;
constexpr float ATT_SCALE = 0.125f;

// workspace layout (float-slot offsets)
constexpr size_t SZ_T = (size_t)BATCH * 197 * 768;            // 4,841,472
constexpr size_t OFF_T0 = 0;
constexpr size_t OFF_T1 = SZ_T;
constexpr size_t OFF_C32 = 2 * SZ_T;                          // 14,524,416 floats
constexpr size_t OFF_ABF = OFF_C32 + (size_t)BATCH * 197 * 2304;   // bf16 activations (2,420,736 slots)
constexpr size_t OFF_WL  = OFF_ABF + 2420736;                 // bf16 weights: 7,667,712 bf16 = 3,833,856 float slots
constexpr size_t OFF_GLOB  = OFF_WL + 3833856;
constexpr size_t OFF_SCORE = OFF_GLOB + (size_t)BATCH * 384;
constexpr size_t OFF_KIDX  = OFF_SCORE + (size_t)BATCH * L0TOK;
constexpr size_t OFF_CLS   = OFF_KIDX + (size_t)BATCH * 140;

// per-layer bf16 weight sub-offsets (bf16-element units)
constexpr size_t W_QKV  = 0;               // 2304*768 = 1,769,472
constexpr size_t W_PROJ = 1769472;         // 768*768  =   589,824
constexpr size_t W_FC1  = 2359296;         // 3072*768 = 2,359,296
constexpr size_t W_FC2  = 4718592;         // 768*3072 = 2,359,296
constexpr size_t W_PIN  = 7077888;         // 768*768  =   589,824

typedef __attribute__((ext_vector_type(8))) short short8;
typedef __attribute__((ext_vector_type(4))) float float4v;

__device__ __forceinline__ float gelu_f(float x) {
    return 0.5f * x * (1.0f + erff(x * 0.7071067811865476f));
}
__device__ __forceinline__ float bf2f(short s) {
    return __uint_as_float(((unsigned)(unsigned short)s) << 16);
}

// async 16B global->LDS (DMA, no VGPR round trip)
__device__ __forceinline__ void load_lds16(const void* g, void* l) {
    __builtin_amdgcn_global_load_lds(
        (const __attribute__((address_space(1))) unsigned int*)g,
        (__attribute__((address_space(3))) unsigned int*)l, 16, 0, 0);
}

// bijective XCD-aware block remap (m204 formula): co-resident blocks on one
// XCD become a contiguous chunk of the linearized grid -> per-XCD L2 reuse.
__device__ __forceinline__ void xcd_swizzle(int& bx, int& by) {
    int gx = gridDim.x, gy = gridDim.y;
    int nwg = gx * gy;
    int orig = blockIdx.y * gx + blockIdx.x;
    int q = nwg >> 3, r = nwg & 7;
    int xcd = orig & 7, loc = orig >> 3;
    int wgid = (xcd < r) ? xcd * (q + 1) + loc : r * (q + 1) + (xcd - r) * q + loc;
    bx = wgid % gx;
    by = wgid / gx;
}

// ---------------- fp32 -> bf16 weight conversion ----------------
__global__ void cvt_kernel(const float* __restrict__ src, __hip_bfloat16* __restrict__ dst, int n) {
    int i = (blockIdx.x * 256 + threadIdx.x) * 4;
    if (i >= n) return;
    float4 v = *(const float4*)(src + i);
    dst[i + 0] = __float2bfloat16(v.x);
    dst[i + 1] = __float2bfloat16(v.y);
    dst[i + 2] = __float2bfloat16(v.z);
    dst[i + 3] = __float2bfloat16(v.w);
}
static inline void cvt(hipStream_t st, const float* s, __hip_bfloat16* d, size_t n) {
    cvt_kernel<<<(n / 4 + 255) / 256, 256, 0, st>>>(s, d, (int)n);
}

// fused per-layer weight convert: qkv|proj|fc1|fc2[|pin] in one launch.
__global__ void cvt_layer_kernel(const float* __restrict__ wqkv, const float* __restrict__ wproj,
                                 const float* __restrict__ wfc1, const float* __restrict__ wfc2,
                                 const float* __restrict__ wpin, __hip_bfloat16* __restrict__ dst) {
    size_t i = ((size_t)blockIdx.x * 256 + threadIdx.x) * 8;
    const float* src;
    size_t off;
    if (i < W_PROJ)      { src = wqkv;  off = i; }
    else if (i < W_FC1)  { src = wproj; off = i - W_PROJ; }
    else if (i < W_FC2)  { src = wfc1;  off = i - W_FC1; }
    else if (i < W_PIN)  { src = wfc2;  off = i - W_FC2; }
    else                 { src = wpin;  off = i - W_PIN; }
    float4 a = *(const float4*)(src + off);
    float4 b = *(const float4*)(src + off + 4);
    union { short8 v; __hip_bfloat16 h[8]; } u;
    u.h[0] = __float2bfloat16(a.x); u.h[1] = __float2bfloat16(a.y);
    u.h[2] = __float2bfloat16(a.z); u.h[3] = __float2bfloat16(a.w);
    u.h[4] = __float2bfloat16(b.x); u.h[5] = __float2bfloat16(b.y);
    u.h[6] = __float2bfloat16(b.z); u.h[7] = __float2bfloat16(b.w);
    *(short8*)(dst + i) = u.v;
}

// ---------------- patch rearrange (bf16 out) ----------------
__global__ void patch_kernel(const float* __restrict__ x, __hip_bfloat16* __restrict__ p) {
    int idx = blockIdx.x * 256 + threadIdx.x;
    int c = idx % 768;
    int rest = idx / 768;
    int l = rest % 196;
    int b = rest / 196;
    int ch = c >> 8;
    int py = (c & 255) >> 4;
    int px = c & 15;
    int gy = l / 14, gx = l % 14;
    p[idx] = __float2bfloat16(
        x[(((size_t)b * 3 + ch) * 224 + gy * 16 + py) * 224 + gx * 16 + px]);
}

// ---------------- assemble t = [cls; patches] + pos (fp32) ----------------
__global__ void assemble_kernel(const float* __restrict__ pe, const float* __restrict__ cls,
                                const float* __restrict__ pos, float* __restrict__ t) {
    int row = blockIdx.x;
    int b = row / 197, l = row % 197;
    for (int c = threadIdx.x; c < 768; c += 256) {
        float v = (l == 0) ? cls[c] : pe[((size_t)(b * 196 + l - 1)) * 768 + c];
        t[(size_t)row * 768 + c] = v + pos[l * 768 + c];
    }
}

// ---------------- layernorm, templated output type ----------------
template <typename OT>
__global__ __launch_bounds__(256)
void ln_kernel(const float* __restrict__ src, OT* __restrict__ dst,
               const float* __restrict__ g, const float* __restrict__ bb,
               int R, int SB, int SO, int DB, int DO_) {
    __shared__ float red[256];
    int row = blockIdx.x;
    int b = row / R, r = row % R;
    const float* sp = src + ((size_t)b * SB + SO + r) * 768;
    OT* dp = dst + ((size_t)b * DB + DO_ + r) * 768;
    int tid = threadIdx.x;
    float x0 = sp[tid], x1 = sp[tid + 256], x2 = sp[tid + 512];
    red[tid] = x0 + x1 + x2;
    __syncthreads();
    for (int st = 128; st > 0; st >>= 1) {
        if (tid < st) red[tid] += red[tid + st];
        __syncthreads();
    }
    float mean = red[0] * (1.0f / 768.0f);
    __syncthreads();
    float d0 = x0 - mean, d1 = x1 - mean, d2 = x2 - mean;
    red[tid] = d0 * d0 + d1 * d1 + d2 * d2;
    __syncthreads();
    for (int st = 128; st > 0; st >>= 1) {
        if (tid < st) red[tid] += red[tid + st];
        __syncthreads();
    }
    float inv = rsqrtf(red[0] * (1.0f / 768.0f) + 1e-6f);
    dp[tid]       = (OT)(d0 * inv * g[tid]       + bb[tid]);
    dp[tid + 256] = (OT)(d1 * inv * g[tid + 256] + bb[tid + 256]);
    dp[tid + 512] = (OT)(d2 * inv * g[tid + 512] + bb[tid + 512]);
}

// ---------------- MFMA GEMM: C = A(MxK,bf16) @ W(NxK,bf16)^T + bias ----------------
template <int EPI, typename CT>
__global__ __launch_bounds__(256)
void gemm_mfma(const __hip_bfloat16* __restrict__ A, const __hip_bfloat16* __restrict__ W,
               const float* __restrict__ bias, const float* __restrict__ res,
               CT* __restrict__ C, int M, int N, int K) {
    __shared__ __hip_bfloat16 As[128 * 32];
    __shared__ __hip_bfloat16 Bs[128 * 32];
    int tid = threadIdx.x;
    int lane = tid & 63;
    int wave = tid >> 6;
    int bx, by;
    xcd_swizzle(bx, by);
    int m0 = by * 128, n0 = bx * 128;
    int wm = (wave >> 1) * 64, wn = (wave & 1) * 64;

    int c0 = tid, c1 = tid + 256;
    int ra0 = c0 >> 2, ka0 = (c0 & 3) << 3;
    int ra1 = c1 >> 2, ka1 = (c1 & 3) << 3;
    const __hip_bfloat16* pa0 = A + (size_t)(m0 + ra0) * K + ka0;
    const __hip_bfloat16* pa1 = A + (size_t)(m0 + ra1) * K + ka1;
    const __hip_bfloat16* pb0 = W + (size_t)(n0 + ra0) * K + ka0;
    const __hip_bfloat16* pb1 = W + (size_t)(n0 + ra1) * K + ka1;
    __hip_bfloat16* la0 = &As[c0 * 8];
    __hip_bfloat16* la1 = &As[c1 * 8];
    __hip_bfloat16* lb0 = &Bs[c0 * 8];
    __hip_bfloat16* lb1 = &Bs[c1 * 8];
    bool va0 = (m0 + ra0) < M, va1 = (m0 + ra1) < M;

    const short* Asp = (const short*)As + (wm + (lane & 15)) * 32 + (lane >> 4) * 8;
    const short* Bsp = (const short*)Bs + (wn + (lane & 15)) * 32 + (lane >> 4) * 8;

    float4v acc[4][4] = {};
    for (int kb = 0; kb < K; kb += 32) {
        if (va0) load_lds16(pa0, la0);
        if (va1) load_lds16(pa1, la1);
        load_lds16(pb0, lb0);
        load_lds16(pb1, lb1);
        pa0 += 32; pa1 += 32; pb0 += 32; pb1 += 32;
        __syncthreads();
        short8 a[4], b[4];
#pragma unroll
        for (int i = 0; i < 4; i++) a[i] = *(const short8*)(Asp + i * 512);
#pragma unroll
        for (int j = 0; j < 4; j++) b[j] = *(const short8*)(Bsp + j * 512);
#pragma unroll
        for (int i = 0; i < 4; i++)
#pragma unroll
            for (int j = 0; j < 4; j++)
                acc[i][j] = __builtin_amdgcn_mfma_f32_16x16x32_bf16(a[i], b[j], acc[i][j], 0, 0, 0);
        __syncthreads();
    }
    int rbase = m0 + wm + (lane >> 4) * 4;
    int cbase = n0 + wn + (lane & 15);
    float bi[4];
#pragma unroll
    for (int j = 0; j < 4; j++) bi[j] = bias[cbase + j * 16];
#pragma unroll
    for (int i = 0; i < 4; i++) {
#pragma unroll
        for (int r = 0; r < 4; r++) {
            int row = rbase + i * 16 + r;
            if (row >= M) continue;
#pragma unroll
            for (int j = 0; j < 4; j++) {
                int col = cbase + j * 16;
                float v = acc[i][j][r] + bi[j];
                if (EPI == 1) v = gelu_f(v);
                if (EPI == 2) v += res[(size_t)row * N + col];
                C[(size_t)row * N + col] = (CT)v;
            }
        }
    }
}

// 128x64 tile variant — for small grids / narrow N (late layers, predictor).
template <int EPI, typename CT>
__global__ __launch_bounds__(256)
void gemm_mfma_n64(const __hip_bfloat16* __restrict__ A, const __hip_bfloat16* __restrict__ W,
                   const float* __restrict__ bias, const float* __restrict__ res,
                   CT* __restrict__ C, int M, int N, int K) {
    __shared__ __hip_bfloat16 As[128 * 32];
    __shared__ __hip_bfloat16 Bs[64 * 32];
    int tid = threadIdx.x;
    int lane = tid & 63;
    int wave = tid >> 6;
    int bx, by;
    xcd_swizzle(bx, by);
    int m0 = by * 128, n0 = bx * 64;
    int wm = (wave >> 1) * 64, wn = (wave & 1) * 32;

    int c0 = tid, c1 = tid + 256;
    int ra0 = c0 >> 2, ka0 = (c0 & 3) << 3;
    int ra1 = c1 >> 2, ka1 = (c1 & 3) << 3;
    int rb  = tid >> 2, kb_ = (tid & 3) << 3;
    const __hip_bfloat16* pa0 = A + (size_t)(m0 + ra0) * K + ka0;
    const __hip_bfloat16* pa1 = A + (size_t)(m0 + ra1) * K + ka1;
    const __hip_bfloat16* pb  = W + (size_t)(n0 + rb) * K + kb_;
    __hip_bfloat16* la0 = &As[c0 * 8];
    __hip_bfloat16* la1 = &As[c1 * 8];
    __hip_bfloat16* lb  = &Bs[tid * 8];
    bool va0 = (m0 + ra0) < M, va1 = (m0 + ra1) < M;

    const short* Asp = (const short*)As + (wm + (lane & 15)) * 32 + (lane >> 4) * 8;
    const short* Bsp = (const short*)Bs + (wn + (lane & 15)) * 32 + (lane >> 4) * 8;

    float4v acc[4][2] = {};
    for (int kb = 0; kb < K; kb += 32) {
        if (va0) load_lds16(pa0, la0);
        if (va1) load_lds16(pa1, la1);
        load_lds16(pb, lb);
        pa0 += 32; pa1 += 32; pb += 32;
        __syncthreads();
        short8 a[4], b[2];
#pragma unroll
        for (int i = 0; i < 4; i++) a[i] = *(const short8*)(Asp + i * 512);
#pragma unroll
        for (int j = 0; j < 2; j++) b[j] = *(const short8*)(Bsp + j * 512);
#pragma unroll
        for (int i = 0; i < 4; i++)
#pragma unroll
            for (int j = 0; j < 2; j++)
                acc[i][j] = __builtin_amdgcn_mfma_f32_16x16x32_bf16(a[i], b[j], acc[i][j], 0, 0, 0);
        __syncthreads();
    }
    int rbase = m0 + wm + (lane >> 4) * 4;
    int cbase = n0 + wn + (lane & 15);
    float bi[2];
#pragma unroll
    for (int j = 0; j < 2; j++) bi[j] = bias[cbase + j * 16];
#pragma unroll
    for (int i = 0; i < 4; i++) {
#pragma unroll
        for (int r = 0; r < 4; r++) {
            int row = rbase + i * 16 + r;
            if (row >= M) continue;
#pragma unroll
            for (int j = 0; j < 2; j++) {
                int col = cbase + j * 16;
                float v = acc[i][j][r] + bi[j];
                if (EPI == 1) v = gelu_f(v);
                if (EPI == 2) v += res[(size_t)row * N + col];
                C[(size_t)row * N + col] = (CT)v;
            }
        }
    }
}

template <typename CT>
static inline void gemm_bf(hipStream_t st, const __hip_bfloat16* A, const __hip_bfloat16* W,
                           const float* bias, const float* res, CT* C,
                           int M, int N, int K, int epi) {
    long blocks128 = (long)(N / 128) * ((M + 127) / 128);
    if (N % 128 == 0 && blocks128 >= 160) {
        dim3 g(N / 128, (M + 127) / 128), b(256);
        if (epi == 0)      gemm_mfma<0, CT><<<g, b, 0, st>>>(A, W, bias, res, C, M, N, K);
        else if (epi == 1) gemm_mfma<1, CT><<<g, b, 0, st>>>(A, W, bias, res, C, M, N, K);
        else               gemm_mfma<2, CT><<<g, b, 0, st>>>(A, W, bias, res, C, M, N, K);
    } else {
        dim3 g(N / 64, (M + 127) / 128), b(256);
        if (epi == 0)      gemm_mfma_n64<0, CT><<<g, b, 0, st>>>(A, W, bias, res, C, M, N, K);
        else if (epi == 1) gemm_mfma_n64<1, CT><<<g, b, 0, st>>>(A, W, bias, res, C, M, N, K);
        else               gemm_mfma_n64<2, CT><<<g, b, 0, st>>>(A, W, bias, res, C, M, N, K);
    }
}

// ---------------- head: C(32x1000) = CLS(32x768) @ head_w(1000x768)^T + b ----------
// 125 blocks x 256 thr; block stages 8 W rows in LDS; thread (m, nl) owns one output.
__global__ __launch_bounds__(256)
void head_kernel(const float* __restrict__ A, const float* __restrict__ W,
                 const float* __restrict__ bias, float* __restrict__ C) {
    __shared__ float Wl[8][768];
    int n0 = blockIdx.x * 8;
    int tid = threadIdx.x;
    for (int i = tid; i < 8 * 192; i += 256) {
        int r = i / 192, c4 = (i % 192) * 4;
        *(float4*)&Wl[r][c4] = *(const float4*)(W + (size_t)(n0 + r) * 768 + c4);
    }
    __syncthreads();
    int m = tid & 31, nl = tid >> 5;
    const float* a = A + m * 768;
    float acc = 0.f;
    for (int k = 0; k < 768; k += 4) {
        float4 av = *(const float4*)(a + k);
        float4 wv = *(const float4*)&Wl[nl][k];
        acc += av.x * wv.x + av.y * wv.y + av.z * wv.z + av.w * wv.w;
    }
    C[m * 1000 + n0 + nl] = acc + bias[n0 + nl];
}

// ---------------- MFMA attention: block per (b,h,32-query tile), bf16 in/out ----------
constexpr int SSTR = 205;
constexpr int PSTR = 264;

__global__ __launch_bounds__(256)
void attn_mfma(const __hip_bfloat16* __restrict__ qkv, __hip_bfloat16* __restrict__ o,
               int L, int QT) {
    __shared__ __hip_bfloat16 Qs[32 * 72];
    __shared__ __hip_bfloat16 Ks[64 * 72];      // K chunk in pass 1, V^T chunk in pass 2
    __shared__ float Ss[32 * SSTR];
    __shared__ __hip_bfloat16 Ps[32 * PSTR];
    __shared__ float red8[256];
    __shared__ float rowstat[32];
    int tid = threadIdx.x;
    int lane = tid & 63;
    int wave = tid >> 6;
    int idx = blockIdx.x;
    int qt = idx % QT; idx /= QT;
    int h = idx % NHEAD;
    int b = idx / NHEAD;
    int q0 = qt * 32;
    const __hip_bfloat16* base = qkv + (size_t)b * L * 2304 + h * 64;
    int fr = lane & 15, fg = lane >> 4;

    {
        int row = tid >> 3, dg = (tid & 7) * 8;
        short8 s = {0, 0, 0, 0, 0, 0, 0, 0};
        if (q0 + row < L) s = *(const short8*)(base + (size_t)(q0 + row) * 2304 + dg);
        *(short8*)&Qs[row * 72 + dg] = s;
    }
    int nchunk = (L + 63) >> 6;
    short8 aq[2][2];

    // ---- pass 1: S = Q K^T * scale ----
    for (int jc = 0; jc < nchunk; jc++) {
        __syncthreads();
        {
            int key = tid >> 2, dg = (tid & 3) * 16;
            int j = jc * 64 + key;
            short8 s0 = {0, 0, 0, 0, 0, 0, 0, 0}, s1 = s0;
            if (j < L) {
                const __hip_bfloat16* src = base + (size_t)j * 2304 + 768 + dg;
                s0 = *(const short8*)src;
                s1 = *(const short8*)(src + 8);
            }
            *(short8*)&Ks[key * 72 + dg] = s0;
            *(short8*)&Ks[key * 72 + dg + 8] = s1;
        }
        __syncthreads();
        if (jc == 0) {
#pragma unroll
            for (int qi = 0; qi < 2; qi++)
#pragma unroll
                for (int kh = 0; kh < 2; kh++)
                    aq[qi][kh] = *(const short8*)&Qs[(qi * 16 + fr) * 72 + kh * 32 + fg * 8];
        }
        short8 bk[2];
#pragma unroll
        for (int kh = 0; kh < 2; kh++)
            bk[kh] = *(const short8*)&Ks[(wave * 16 + fr) * 72 + kh * 32 + fg * 8];
        int col = jc * 64 + wave * 16 + fr;
#pragma unroll
        for (int qi = 0; qi < 2; qi++) {
            float4v acc = {};
            acc = __builtin_amdgcn_mfma_f32_16x16x32_bf16(aq[qi][0], bk[0], acc, 0, 0, 0);
            acc = __builtin_amdgcn_mfma_f32_16x16x32_bf16(aq[qi][1], bk[1], acc, 0, 0, 0);
            if (col < L) {
#pragma unroll
                for (int r = 0; r < 4; r++)
                    Ss[(qi * 16 + fg * 4 + r) * SSTR + col] = acc[r] * ATT_SCALE;
            }
        }
    }
    __syncthreads();

    // ---- softmax (8 threads per row), P -> bf16, zero-padded to nchunk*64 ----
    {
        int q = tid & 31, c = tid >> 5;
        float mx = -1e30f;
        for (int j = c; j < L; j += 8) mx = fmaxf(mx, Ss[q * SSTR + j]);
        red8[c * 32 + q] = mx;
        __syncthreads();
        if (tid < 32) {
            float m2 = red8[tid];
#pragma unroll
            for (int cc = 1; cc < 8; cc++) m2 = fmaxf(m2, red8[cc * 32 + tid]);
            rowstat[tid] = m2;
        }
        __syncthreads();
        mx = rowstat[q];
        float sm = 0.f;
        int NC64 = nchunk * 64;
        for (int j = c; j < NC64; j += 8) {
            float e = 0.f;
            if (j < L) { e = __expf(Ss[q * SSTR + j] - mx); sm += e; }
            Ps[q * PSTR + j] = __float2bfloat16(e);
        }
        red8[c * 32 + q] = sm;
        __syncthreads();
        if (tid < 32) {
            float s2 = red8[tid];
#pragma unroll
            for (int cc = 1; cc < 8; cc++) s2 += red8[cc * 32 + tid];
            rowstat[tid] = 1.0f / s2;
        }
    }

    // ---- pass 2: O = P V ----
    float4v acco[2] = {};
    for (int jc = 0; jc < nchunk; jc++) {
        __syncthreads();
        {
            int key = tid >> 2, dg = (tid & 3) * 16;
            int j = jc * 64 + key;
            short8 s0 = {0, 0, 0, 0, 0, 0, 0, 0}, s1 = s0;
            if (j < L) {
                const __hip_bfloat16* src = base + (size_t)j * 2304 + 1536 + dg;
                s0 = *(const short8*)src;
                s1 = *(const short8*)(src + 8);
            }
            const __hip_bfloat16* e0 = (const __hip_bfloat16*)&s0;
            const __hip_bfloat16* e1 = (const __hip_bfloat16*)&s1;
#pragma unroll
            for (int i2 = 0; i2 < 8; i2++) {
                Ks[(dg + i2) * 72 + key] = e0[i2];
                Ks[(dg + 8 + i2) * 72 + key] = e1[i2];
            }
        }
        __syncthreads();
        short8 ap[2][2], bv[2];
#pragma unroll
        for (int kh = 0; kh < 2; kh++)
            bv[kh] = *(const short8*)&Ks[(wave * 16 + fr) * 72 + kh * 32 + fg * 8];
#pragma unroll
        for (int qi = 0; qi < 2; qi++)
#pragma unroll
            for (int kh = 0; kh < 2; kh++)
                ap[qi][kh] = *(const short8*)&Ps[(qi * 16 + fr) * PSTR + jc * 64 + kh * 32 + fg * 8];
#pragma unroll
        for (int qi = 0; qi < 2; qi++) {
            acco[qi] = __builtin_amdgcn_mfma_f32_16x16x32_bf16(ap[qi][0], bv[0], acco[qi], 0, 0, 0);
            acco[qi] = __builtin_amdgcn_mfma_f32_16x16x32_bf16(ap[qi][1], bv[1], acco[qi], 0, 0, 0);
        }
    }
#pragma unroll
    for (int qi = 0; qi < 2; qi++) {
#pragma unroll
        for (int r = 0; r < 4; r++) {
            int q = qi * 16 + fg * 4 + r;
            if (q0 + q < L) {
                float inv = rowstat[q];
                o[((size_t)(b * L + q0 + q)) * 768 + h * 64 + wave * 16 + fr] =
                    __float2bfloat16(acco[qi][r] * inv);
            }
        }
    }
}

// ---------------- predictor helpers (bf16 h) ----------------
__global__ void globpart_kernel(const __hip_bfloat16* __restrict__ hp, float* __restrict__ gp,
                                int Lc) {
    int blk = blockIdx.x;
    int b = blk >> 3, c8 = blk & 7;
    int c = threadIdx.x;
    int chunk = (Lc + 7) / 8;
    int r0 = c8 * chunk, r1 = min(Lc, r0 + chunk);
    float s = 0.f;
    for (int l = r0; l < r1; l++)
        s += __bfloat162float(hp[((size_t)(b * Lc + l)) * 768 + 384 + c]);
    gp[(size_t)blk * 384 + c] = s;
}

__global__ void globred_kernel(const float* __restrict__ gp, float* __restrict__ glob, int Lc) {
    int b = blockIdx.x;
    int c = threadIdx.x;
    float s = 0.f;
#pragma unroll
    for (int j = 0; j < 8; j++) s += gp[(size_t)(b * 8 + j) * 384 + c];
    glob[b * 384 + c] = s / (float)Lc;
}

__global__ void globbcast_bf(__hip_bfloat16* __restrict__ hp, const float* __restrict__ glob,
                             int Lc) {
    int row = blockIdx.x;
    int b = row / Lc;
    int c = threadIdx.x;
    hp[(size_t)row * 768 + 384 + c] = __float2bfloat16(glob[b * 384 + c]);
}

__global__ __launch_bounds__(256)
void score_kernel(const float* __restrict__ p2, const float* __restrict__ w3,
                  const float* __restrict__ b3, float* __restrict__ score) {
    __shared__ float red[256];
    int row = blockIdx.x;
    int tid = threadIdx.x;
    red[tid] = (tid < 192) ? p2[(size_t)row * 192 + tid] * w3[tid] : 0.f;
    __syncthreads();
    for (int st = 128; st > 0; st >>= 1) {
        if (tid < st) red[tid] += red[tid + st];
        __syncthreads();
    }
    if (tid == 0) {
        float x = red[0] + b3[0];
        score[row] = fminf(x, 0.0f) - log1pf(__expf(-fabsf(x)));
    }
}

// ---------------- top-k (set-equivalent to jax.lax.top_k) ----------------
__global__ void topk_kernel(const float* __restrict__ score, int* __restrict__ kidx,
                            int Lc, int k) {
    __shared__ float s[196];
    __shared__ int keep[196];
    int b = blockIdx.x, tid = threadIdx.x;
    for (int i = tid; i < Lc; i += 256) s[i] = score[b * Lc + i];
    __syncthreads();
    for (int i = tid; i < Lc; i += 256) {
        float si = s[i];
        int rank = 0;
        for (int j = 0; j < Lc; j++) {
            float sj = s[j];
            rank += (sj > si) || (sj == si && j < i);
        }
        keep[i] = (rank < k) ? 1 : 0;
    }
    __syncthreads();
    for (int i = tid; i < Lc; i += 256) {
        if (keep[i]) {
            int pos = 0;
            for (int j = 0; j < i; j++) pos += keep[j];
            kidx[b * MAXK + pos] = i;
        }
    }
}

__global__ void gather_kernel(const float* __restrict__ t, const int* __restrict__ kidx,
                              float* __restrict__ dst, int L, int Lnew) {
    int row = blockIdx.x;
    int b = row / Lnew, m = row % Lnew;
    int srcrow = (m == 0) ? b * L : b * L + 1 + kidx[b * MAXK + m - 1];
    const float* sp = t + (size_t)srcrow * 768;
    float* dp = dst + (size_t)row * 768;
    for (int c = threadIdx.x; c < 768; c += 256) dp[c] = sp[c];
}

// ---------------- host orchestration ----------------
extern "C" void kernel_launch(void* const* d_in, const int* in_sizes, int n_in,
                              void* d_out, int out_size, void* d_ws, size_t ws_size,
                              hipStream_t stream) {
    const float* x        = (const float*)d_in[0];
    const float* patch_w  = (const float*)d_in[1];
    const float* patch_b  = (const float*)d_in[2];
    const float* cls_tok  = (const float*)d_in[3];
    const float* pos_emb  = (const float*)d_in[4];
    const float* ln1_g    = (const float*)d_in[5];
    const float* ln1_b    = (const float*)d_in[6];
    const float* qkv_w    = (const float*)d_in[7];
    const float* qkv_b    = (const float*)d_in[8];
    const float* proj_w   = (const float*)d_in[9];
    const float* proj_b   = (const float*)d_in[10];
    const float* ln2_g    = (const float*)d_in[11];
    const float* ln2_b    = (const float*)d_in[12];
    const float* fc1_w    = (const float*)d_in[13];
    const float* fc1_b    = (const float*)d_in[14];
    const float* fc2_w    = (const float*)d_in[15];
    const float* fc2_b    = (const float*)d_in[16];
    const float* pln_g    = (const float*)d_in[17];
    const float* pln_b    = (const float*)d_in[18];
    const float* pin_w    = (const float*)d_in[19];
    const float* pin_b    = (const float*)d_in[20];
    const float* pw1      = (const float*)d_in[21];
    const float* pb1      = (const float*)d_in[22];
    const float* pw2      = (const float*)d_in[23];
    const float* pb2      = (const float*)d_in[24];
    const float* pw3      = (const float*)d_in[25];
    const float* pb3      = (const float*)d_in[26];
    const float* norm_g   = (const float*)d_in[27];
    const float* norm_b   = (const float*)d_in[28];
    const float* head_w   = (const float*)d_in[29];
    const float* head_b   = (const float*)d_in[30];

    float* ws = (float*)d_ws;
    float* cur   = ws + OFF_T0;
    float* tmp   = ws + OFF_T1;
    float* C32   = ws + OFF_C32;
    __hip_bfloat16* ABF = (__hip_bfloat16*)(ws + OFF_ABF);
    __hip_bfloat16* WL  = (__hip_bfloat16*)(ws + OFF_WL);
    __hip_bfloat16* QBF = (__hip_bfloat16*)C32;  // qkv bf16 out overlays C32 region
    __hip_bfloat16* BBF = (__hip_bfloat16*)C32;  // fc1 bf16 out overlays C32 region
    float* GLOB  = ws + OFF_GLOB;
    float* SCORE = ws + OFF_SCORE;
    int*   KIDX  = (int*)(ws + OFF_KIDX);
    float* CLS   = ws + OFF_CLS;

    // patch embed
    cvt(stream, patch_w, WL, 768 * 768);
    patch_kernel<<<(BATCH * 196 * 768) / 256, 256, 0, stream>>>(x, ABF);
    gemm_bf<float>(stream, ABF, WL, patch_b, nullptr, C32, BATCH * 196, 768, 768, 0);
    assemble_kernel<<<BATCH * 197, 256, 0, stream>>>(C32, cls_tok, pos_emb, cur);

    int L = 197;
    for (int i = 0; i < DEPTH; i++) {
        bool isprune = (i == 3 || i == 6 || i == 9);
        // fused per-layer weight conversion (single launch)
        {
            int nblk = isprune ? 3744 : 3456;
            const float* pin_src = isprune ? pin_w + (size_t)(i / 3 - 1) * 768 * 768 : qkv_w;
            cvt_layer_kernel<<<nblk, 256, 0, stream>>>(
                qkv_w + (size_t)i * 2304 * 768, proj_w + (size_t)i * 768 * 768,
                fc1_w + (size_t)i * 3072 * 768, fc2_w + (size_t)i * 768 * 3072,
                pin_src, WL);
        }
        if (isprune) {
            int s = i / 3 - 1;
            int Lc = L - 1;
            int k = (7 * Lc + 9) / 10;  // ceil(0.7*Lc)
            int Mp = BATCH * Lc;
            // predictor scratch lives in the (currently dead) tmp region
            __hip_bfloat16* HBF   = (__hip_bfloat16*)C32;          // pin out, M x 768 bf16
            __hip_bfloat16* PW1BF = (__hip_bfloat16*)tmp;          // 384*768 bf16
            __hip_bfloat16* PW2BF = (__hip_bfloat16*)(tmp + 150000);
            __hip_bfloat16* P1BF  = (__hip_bfloat16*)(tmp + 200000);  // M x 384 bf16
            float* P2 = tmp + 1500000;                             // M x 192 fp32
            float* GP = tmp + 3000000;                             // 32*8*384 fp32

            ln_kernel<__hip_bfloat16><<<Mp, 256, 0, stream>>>(
                cur, ABF, pln_g + s * 768, pln_b + s * 768, Lc, L, 1, Lc, 0);
            cvt(stream, pw1 + (size_t)s * 384 * 768, PW1BF, 384 * 768);
            cvt(stream, pw2 + (size_t)s * 192 * 384, PW2BF, 192 * 384);
            gemm_bf<__hip_bfloat16>(stream, ABF, WL + W_PIN, pin_b + s * 768, nullptr, HBF,
                                    Mp, 768, 768, 1);
            globpart_kernel<<<BATCH * 8, 384, 0, stream>>>(HBF, GP, Lc);
            globred_kernel<<<BATCH, 384, 0, stream>>>(GP, GLOB, Lc);
            globbcast_bf<<<Mp, 384, 0, stream>>>(HBF, GLOB, Lc);
            gemm_bf<__hip_bfloat16>(stream, HBF, PW1BF, pb1 + s * 384, nullptr, P1BF,
                                    Mp, 384, 768, 1);
            gemm_bf<float>(stream, P1BF, PW2BF, pb2 + s * 192, nullptr, P2,
                           Mp, 192, 384, 1);
            score_kernel<<<Mp, 256, 0, stream>>>(P2, pw3 + s * 192, pb3 + s, SCORE);
            topk_kernel<<<BATCH, 256, 0, stream>>>(SCORE, KIDX, Lc, k);
            int Lnew = k + 1;
            gather_kernel<<<BATCH * Lnew, 256, 0, stream>>>(cur, KIDX, tmp, L, Lnew);
            float* t_ = cur; cur = tmp; tmp = t_;
            L = Lnew;
        }
        int M = BATCH * L;
        int QT = (L + 31) / 32;
        // attention
        ln_kernel<__hip_bfloat16><<<M, 256, 0, stream>>>(
            cur, ABF, ln1_g + i * 768, ln1_b + i * 768, L, L, 0, L, 0);
        gemm_bf<__hip_bfloat16>(stream, ABF, WL + W_QKV, qkv_b + i * 2304, nullptr, QBF,
                                M, 2304, 768, 0);
        attn_mfma<<<BATCH * NHEAD * QT, 256, 0, stream>>>(QBF, ABF, L, QT);
        gemm_bf<float>(stream, ABF, WL + W_PROJ, proj_b + i * 768, cur, cur, M, 768, 768, 2);
        // MLP
        ln_kernel<__hip_bfloat16><<<M, 256, 0, stream>>>(
            cur, ABF, ln2_g + i * 768, ln2_b + i * 768, L, L, 0, L, 0);
        gemm_bf<__hip_bfloat16>(stream, ABF, WL + W_FC1, fc1_b + i * 3072, nullptr, BBF,
                                M, 3072, 768, 1);
        gemm_bf<float>(stream, BBF, WL + W_FC2, fc2_b + i * 768, cur, cur, M, 768, 3072, 2);
    }
    ln_kernel<float><<<BATCH, 256, 0, stream>>>(cur, CLS, norm_g, norm_b, 1, L, 0, 1, 0);
    head_kernel<<<125, 256, 0, stream>>>(CLS, head_w, head_b, (float*)d_out);
}